// Round 8
// baseline (222.240 us; speedup 1.0000x reference)
//
#include <hip/hip_runtime.h>
#include <hip/hip_bf16.h>

#define D_MODEL 1024
#define N_HEADS 16
#define HEAD_DIM 64
#define SEQ 2048
#define BATCH 2

typedef __attribute__((ext_vector_type(8))) short bf16x8;
typedef __attribute__((ext_vector_type(4))) float f32x4;
typedef __attribute__((ext_vector_type(16))) float f32x16;

typedef __attribute__((address_space(3))) unsigned lds_uint;
typedef __attribute__((address_space(1))) const unsigned global_cuint;

__device__ __forceinline__ void async_cp16(const ushort* g, ushort* l) {
  __builtin_amdgcn_global_load_lds((global_cuint*)g, (lds_uint*)l, 16, 0, 0);
}

__device__ __forceinline__ ushort f2b(float f) {
  union { float f; unsigned u; } x; x.f = f;
  unsigned r = x.u + 0x7fffu + ((x.u >> 16) & 1u);
  return (ushort)(r >> 16);
}

// packed f32x2 -> bf16x2; low word = a
__device__ __forceinline__ unsigned pk2(float a, float b) {
  __hip_bfloat162 h = __float22bfloat162_rn(float2{a, b});
  union { __hip_bfloat162 h; unsigned u; } x; x.h = h;
  return x.u;
}

__device__ __forceinline__ float blo(unsigned u) {
  union { unsigned u; float f; } x; x.u = u << 16; return x.f;
}
__device__ __forceinline__ float bhi(unsigned u) {
  union { unsigned u; float f; } x; x.u = u & 0xffff0000u; return x.f;
}

// XOR-swizzled ushort index into a [64][64] (128 B/row) LDS tile.
// byte_off within row ^= (row&7)<<4. With pre-swizzled global staging
// (source 16B-slot = (l&7)^(l>>3)) the staging write is lane-linear and
// all b128 frag reads distribute exactly 8 lanes per 16B slot.
__device__ __forceinline__ int swz64(int row, int colbyte) {
  return row * 64 + ((colbyte ^ ((row & 7) << 4)) >> 1);
}

// Single fused cast: x (1M uint4) + Wq/Wk/Wv (-> wqkv) + Wo (-> wob).
__global__ __launch_bounds__(256) void cast_all(const float* __restrict__ x,
                                                const float* __restrict__ Wq,
                                                const float* __restrict__ Wk,
                                                const float* __restrict__ Wv,
                                                const float* __restrict__ Wo,
                                                ushort* __restrict__ xb,
                                                ushort* __restrict__ wqkv,
                                                ushort* __restrict__ wob) {
  int idx = blockIdx.x * 256 + threadIdx.x;  // 0 .. 2M-1 (uint4 units)
  const float* in;
  uint2* out;
  if (idx < (1 << 20)) {
    in = x; out = (uint2*)xb;
  } else {
    int j = idx - (1 << 20);
    int w = j >> 18;            // 0..3
    idx = j & 0x3FFFF;          // 256K uint4 per weight
    switch (w) {
      case 0: in = Wq; out = (uint2*)wqkv; break;
      case 1: in = Wk; out = (uint2*)(wqkv) + (1 << 18); break;
      case 2: in = Wv; out = (uint2*)(wqkv) + (2 << 18); break;
      default: in = Wo; out = (uint2*)wob; break;
    }
  }
  float4 v = ((const float4*)in)[idx];
  uint2 o; o.x = pk2(v.x, v.y); o.y = pk2(v.z, v.w);
  out[idx] = o;
}

// Fused QKV projection: A = xb (4096x1024 bf16), Bw = wqkv (3072x1024 bf16).
// 128x128 tile, BK=64 (16 K-iters). Dbuf LDS, 1 barrier/K-step, swizzled.
__global__ __launch_bounds__(256) void gemm_qkv(const ushort* __restrict__ A,
                                                const ushort* __restrict__ Bw,
                                                ushort* __restrict__ Qh,
                                                ushort* __restrict__ Kh,
                                                ushort* __restrict__ Vth,
                                                float qscale) {
  constexpr int K = 1024;
  const int bm = blockIdx.y * 128;
  const int bn = blockIdx.x * 128;
  const int tid = threadIdx.x;
  const int wave = tid >> 6;
  const int lane = tid & 63;
  const int l16 = lane & 15;
  const int quad = lane >> 4;

  __shared__ ushort As[2][128 * 64];   // 32 KB (dbuf)
  __shared__ ushort Bs[2][128 * 64];   // 32 KB (dbuf)

  const int wm = (wave & 1) * 64;
  const int wn = (wave >> 1) * 64;

  f32x4 acc[4][4];
#pragma unroll
  for (int r = 0; r < 4; ++r)
#pragma unroll
    for (int c = 0; c < 4; ++c) acc[r][c] = (f32x4){0.f, 0.f, 0.f, 0.f};

  const int srow = wave * 8 + (lane >> 3);
  const int csw = (((lane & 7) ^ (lane >> 3)) << 3);  // pre-swizzled col (ushorts)

  // prologue: tile 0 -> buf 0
#pragma unroll
  for (int j = 0; j < 4; ++j) {
    async_cp16(A  + (size_t)(bm + j * 32 + srow) * K + csw, &As[0][(j * 32 + wave * 8) * 64]);
    async_cp16(Bw + (size_t)(bn + j * 32 + srow) * K + csw, &Bs[0][(j * 32 + wave * 8) * 64]);
  }

  constexpr int NIT = K / 64;  // 16
  for (int kt = 0; kt < NIT; ++kt) {
    __syncthreads();  // vmcnt(0) drain: tile kt landed; prior reads of buf^1 done
    const int buf = kt & 1;
    if (kt + 1 < NIT) {
      const int k0 = (kt + 1) * 64;
#pragma unroll
      for (int j = 0; j < 4; ++j) {
        async_cp16(A  + (size_t)(bm + j * 32 + srow) * K + k0 + csw, &As[buf ^ 1][(j * 32 + wave * 8) * 64]);
        async_cp16(Bw + (size_t)(bn + j * 32 + srow) * K + k0 + csw, &Bs[buf ^ 1][(j * 32 + wave * 8) * 64]);
      }
    }

    bf16x8 a[2][4], b[2][4];
#pragma unroll
    for (int ks = 0; ks < 2; ++ks)
#pragma unroll
      for (int r = 0; r < 4; ++r) {
        a[ks][r] = *(const bf16x8*)(&As[buf][swz64(wm + r * 16 + l16, ks * 64 + quad * 16)]);
        b[ks][r] = *(const bf16x8*)(&Bs[buf][swz64(wn + r * 16 + l16, ks * 64 + quad * 16)]);
      }
#pragma unroll
    for (int ks = 0; ks < 2; ++ks)
#pragma unroll
      for (int r = 0; r < 4; ++r)
#pragma unroll
        for (int c = 0; c < 4; ++c)
          acc[r][c] = __builtin_amdgcn_mfma_f32_16x16x32_bf16(a[ks][r], b[ks][c], acc[r][c], 0, 0, 0);
  }

#pragma unroll
  for (int r = 0; r < 4; ++r) {
#pragma unroll
    for (int c = 0; c < 4; ++c) {
      int ncol = bn + wn + c * 16 + l16;   // 0..3071; w uniform per (block,wave)
      int w = ncol >> 10;
      int f = ncol & 1023;
      int h = f >> 6, d = f & 63;
      if (w == 2) {
        // V^T: 4 consecutive tokens per lane -> one b64 store
        int m0 = bm + wm + r * 16 + quad * 4;
        int b = m0 >> 11, t0 = m0 & 2047;
        uint2 pp;
        pp.x = pk2(acc[r][c][0], acc[r][c][1]);
        pp.y = pk2(acc[r][c][2], acc[r][c][3]);
        *(uint2*)(&Vth[((size_t)(b * 1024 + f) << 11) + t0]) = pp;
      } else {
#pragma unroll
        for (int rr = 0; rr < 4; ++rr) {
          float v = acc[r][c][rr];
          int m = bm + wm + r * 16 + quad * 4 + rr;
          int b = m >> 11, t = m & 2047;
          if (w == 0)
            Qh[((size_t)(b * 16 + h) * SEQ + t) * 64 + d] = f2b(v * qscale);
          else
            Kh[((size_t)(b * 16 + h) * SEQ + t) * 64 + d] = f2b(v);
        }
      }
    }
  }
}

// Output projection: A = ctx (4096x1024 bf16), Bw = wob, fp32 out.
// 64x128 tile, BK=64. Dbuf + swizzle (R15).
__global__ __launch_bounds__(256) void gemm_out(const ushort* __restrict__ A,
                                                const ushort* __restrict__ Bw,
                                                float* __restrict__ out) {
  constexpr int K = 1024;
  const int bm = blockIdx.y * 64;
  const int bn = blockIdx.x * 128;
  const int tid = threadIdx.x;
  const int wave = tid >> 6;
  const int lane = tid & 63;
  const int l16 = lane & 15;
  const int quad = lane >> 4;

  __shared__ ushort As[2][64 * 64];    // 16 KB (dbuf)
  __shared__ ushort Bs[2][128 * 64];   // 32 KB (dbuf)

  const int wm = (wave & 1) * 32;
  const int wn = (wave >> 1) * 64;

  f32x4 acc[2][4];
#pragma unroll
  for (int r = 0; r < 2; ++r)
#pragma unroll
    for (int c = 0; c < 4; ++c) acc[r][c] = (f32x4){0.f, 0.f, 0.f, 0.f};

  const int srow = wave * 8 + (lane >> 3);
  const int csw = (((lane & 7) ^ (lane >> 3)) << 3);  // pre-swizzled col (ushorts)

  // prologue: tile 0 -> buf 0
#pragma unroll
  for (int j = 0; j < 2; ++j)
    async_cp16(A + (size_t)(bm + j * 32 + srow) * K + csw, &As[0][(j * 32 + wave * 8) * 64]);
#pragma unroll
  for (int j = 0; j < 4; ++j)
    async_cp16(Bw + (size_t)(bn + j * 32 + srow) * K + csw, &Bs[0][(j * 32 + wave * 8) * 64]);

  constexpr int NIT = K / 64;  // 16
  for (int kt = 0; kt < NIT; ++kt) {
    __syncthreads();
    const int buf = kt & 1;
    if (kt + 1 < NIT) {
      const int k0 = (kt + 1) * 64;
#pragma unroll
      for (int j = 0; j < 2; ++j)
        async_cp16(A + (size_t)(bm + j * 32 + srow) * K + k0 + csw, &As[buf ^ 1][(j * 32 + wave * 8) * 64]);
#pragma unroll
      for (int j = 0; j < 4; ++j)
        async_cp16(Bw + (size_t)(bn + j * 32 + srow) * K + k0 + csw, &Bs[buf ^ 1][(j * 32 + wave * 8) * 64]);
    }

    bf16x8 a[2][2], b[2][4];
#pragma unroll
    for (int ks = 0; ks < 2; ++ks) {
#pragma unroll
      for (int r = 0; r < 2; ++r)
        a[ks][r] = *(const bf16x8*)(&As[buf][swz64(wm + r * 16 + l16, ks * 64 + quad * 16)]);
#pragma unroll
      for (int c = 0; c < 4; ++c)
        b[ks][c] = *(const bf16x8*)(&Bs[buf][swz64(wn + c * 16 + l16, ks * 64 + quad * 16)]);
    }
#pragma unroll
    for (int ks = 0; ks < 2; ++ks)
#pragma unroll
      for (int r = 0; r < 2; ++r)
#pragma unroll
        for (int c = 0; c < 4; ++c)
          acc[r][c] = __builtin_amdgcn_mfma_f32_16x16x32_bf16(a[ks][r], b[ks][c], acc[r][c], 0, 0, 0);
  }

#pragma unroll
  for (int r = 0; r < 2; ++r)
#pragma unroll
    for (int c = 0; c < 4; ++c)
#pragma unroll
      for (int rr = 0; rr < 4; ++rr) {
        int m = bm + wm + r * 16 + quad * 4 + rr;
        int n = bn + wn + c * 16 + l16;
        out[(size_t)m * D_MODEL + n] = acc[r][c][rr];
      }
}

// Flash attention, R19: V direct from L2, K-only LDS staging.
// R18 post-mortem: residency is LDS-capped (~5 blocks/CU; counter under-
// reports ~2x) and the wall is the LDS pipe + barrier convoy: 80 KB LDS
// traffic per block-iter (4 waves x 16 KB reads + 16 KB DMA). R19 removes
// the V half: V fragments load straight from global (stream KV is 128 KB,
// XCD-affine -> L2-resident; vb b128 = 32-line x 32 B pairs), issued at the
// top of each kt2 so QK/exp2 covers L2 latency. K stays global_load_lds
// dbuf (16 KB LDS total, also exactly the O-store tile). LDS traffic per
// block-iter: 80 -> 40 KB; V-DMA gone; barrier only sequences K. K-read
// LDS offsets precomputed outside the loop (LICM).
__global__ __launch_bounds__(256, 2) void attn_kernel(const ushort* __restrict__ Qh,
                                                      const ushort* __restrict__ Kh,
                                                      const ushort* __restrict__ Vth,
                                                      ushort* __restrict__ O1,
                                                      ushort* __restrict__ O2,
                                                      ushort* __restrict__ O3,
                                                      ushort* __restrict__ O4,
                                                      float* __restrict__ l1,
                                                      float* __restrict__ l2,
                                                      float* __restrict__ l3,
                                                      float* __restrict__ l4) {
  const int id = blockIdx.x;
  const int stream = id & 127;      // bh*4 + quarter
  const int qb = id >> 7;           // 0..15
  const int bh = stream >> 2;
  const int quarter = stream & 3;
  const int q0 = qb * 128;
  ushort* __restrict__ Op = (quarter == 0) ? O1 : (quarter == 1) ? O2 : (quarter == 2) ? O3 : O4;
  float* __restrict__ lp = (quarter == 0) ? l1 : (quarter == 1) ? l2 : (quarter == 2) ? l3 : l4;

  const int tid = threadIdx.x;
  const int wave = tid >> 6;
  const int lane = tid & 63;
  const int l31 = lane & 31;
  const int hi = lane >> 5;

  __shared__ ushort Kbuf[2][64 * 64];  // 16 KB: K dbuf, swizzled; reused as O tile

  // Q frags (B-op of QK): col = l31 = q, k = d = dc*16 + hi*8 + j
  bf16x8 qf[4];
#pragma unroll
  for (int dc = 0; dc < 4; ++dc)
    qf[dc] = *(const bf16x8*)(Qh + ((size_t)bh * SEQ + q0 + wave * 32 + l31) * 64 + dc * 16 + hi * 8);

  f32x16 o0 = {0.f, 0.f, 0.f, 0.f, 0.f, 0.f, 0.f, 0.f,
               0.f, 0.f, 0.f, 0.f, 0.f, 0.f, 0.f, 0.f};
  f32x16 o1 = o0;
  float lacc = 0.f;

  // K staging geometry: wave fills chunks {2w,2w+1} (8 rows each); source
  // 16B-slot pre-swizzled so the lane-linear LDS write lands at swz64.
  const int chunk = wave * 2;
  const int r8 = lane >> 3;
  const int csw = (((lane & 7) ^ r8) << 3);   // ushort offset within 64
  const ushort* kbase = Kh + ((size_t)bh * SEQ + quarter * 512) * 64;
  const ushort* vbase = Vth + (size_t)bh * 64 * SEQ + quarter * 512;
  const ushort* ksrc = kbase + (size_t)(chunk * 8 + r8) * 64 + csw;   // +kt*4096

  // precomputed K frag LDS offsets (loop-invariant; only buf base toggles)
  int koff[2][4];
#pragma unroll
  for (int kt2 = 0; kt2 < 2; ++kt2)
#pragma unroll
    for (int dc = 0; dc < 4; ++dc)
      koff[kt2][dc] = swz64(kt2 * 32 + l31, dc * 32 + hi * 16);

  // prologue: K tile 0 -> buf 0
  async_cp16(ksrc,          &Kbuf[0][chunk * 512]);
  async_cp16(ksrc + 8 * 64, &Kbuf[0][(chunk + 1) * 512]);

  constexpr int NIT = 512 / 64;  // 8
  for (int kt = 0; kt < NIT; ++kt) {
    __syncthreads();  // drains vmcnt: K tile kt landed; prior reads of buf^1 done
    const int buf = kt & 1;
    if (kt + 1 < NIT) {
      const ushort* ks = ksrc + (size_t)(kt + 1) * 64 * 64;
      async_cp16(ks,          &Kbuf[buf ^ 1][chunk * 512]);
      async_cp16(ks + 8 * 64, &Kbuf[buf ^ 1][(chunk + 1) * 512]);
    }
    const ushort* Kt = Kbuf[buf];

#pragma unroll
    for (int kt2 = 0; kt2 < 2; ++kt2) {
      // V fragments for this 32-key window: direct from global (L2).
      // t = kt*64 + kt2*32 + lw*16 + hi*8, d = l31 (v0*) / 32+l31 (v1*)
      const ushort* vt = vbase + kt * 64 + kt2 * 32 + hi * 8;
      bf16x8 v00 = *(const bf16x8*)(vt + (size_t)l31 * SEQ);
      bf16x8 v01 = *(const bf16x8*)(vt + (size_t)l31 * SEQ + 16);
      bf16x8 v10 = *(const bf16x8*)(vt + (size_t)(32 + l31) * SEQ);
      bf16x8 v11 = *(const bf16x8*)(vt + (size_t)(32 + l31) * SEQ + 16);

      // QK^T: A = K (row = key = kt2*32 + l31, k = d), 4 d-chunks
      bf16x8 ka0 = *(const bf16x8*)(Kt + koff[kt2][0]);
      bf16x8 ka1 = *(const bf16x8*)(Kt + koff[kt2][1]);
      bf16x8 ka2 = *(const bf16x8*)(Kt + koff[kt2][2]);
      bf16x8 ka3 = *(const bf16x8*)(Kt + koff[kt2][3]);
      f32x16 z = {0.f, 0.f, 0.f, 0.f, 0.f, 0.f, 0.f, 0.f,
                  0.f, 0.f, 0.f, 0.f, 0.f, 0.f, 0.f, 0.f};
      z = __builtin_amdgcn_mfma_f32_32x32x16_bf16(ka0, qf[0], z, 0, 0, 0);
      z = __builtin_amdgcn_mfma_f32_32x32x16_bf16(ka1, qf[1], z, 0, 0, 0);
      z = __builtin_amdgcn_mfma_f32_32x32x16_bf16(ka2, qf[2], z, 0, 0, 0);
      z = __builtin_amdgcn_mfma_f32_32x32x16_bf16(ka3, qf[3], z, 0, 0, 0);

      float e[16];
#pragma unroll
      for (int r = 0; r < 16; ++r) e[r] = __builtin_amdgcn_exp2f(z[r]);
      lacc += (((e[0] + e[1]) + (e[2] + e[3])) + ((e[4] + e[5]) + (e[6] + e[7])))
            + (((e[8] + e[9]) + (e[10] + e[11])) + ((e[12] + e[13]) + (e[14] + e[15])));

#pragma unroll
      for (int lw = 0; lw < 2; ++lw) {
        const int base = lw * 8;
        unsigned pa0 = pk2(e[base + 0], e[base + 1]);
        unsigned pa1 = pk2(e[base + 2], e[base + 3]);
        unsigned pa2 = pk2(e[base + 4], e[base + 5]);
        unsigned pa3 = pk2(e[base + 6], e[base + 7]);
        // cross-half exchange: hi=0's (pa2,pa3) <-> hi=1's (pa0,pa1).
        unsigned s0 = hi ? pa0 : pa2;
        unsigned s1 = hi ? pa1 : pa3;
        unsigned t0 = __shfl_xor(s0, 32, 64);
        unsigned t1 = __shfl_xor(s1, 32, 64);
        pa2 = hi ? pa2 : t0;
        pa3 = hi ? pa3 : t1;
        pa0 = hi ? t0 : pa0;
        pa1 = hi ? t1 : pa1;
        union { unsigned u[4]; bf16x8 v; } pu;
        pu.u[0] = pa0; pu.u[1] = pa1; pu.u[2] = pa2; pu.u[3] = pa3;
        o0 = __builtin_amdgcn_mfma_f32_32x32x16_bf16(pu.v, lw ? v01 : v00, o0, 0, 0, 0);
        o1 = __builtin_amdgcn_mfma_f32_32x32x16_bf16(pu.v, lw ? v11 : v10, o1, 0, 0, 0);
      }
    }
  }

  // l: lane and lane+32 hold complementary key-halves of the same q = l31.
  {
    float ltot = lacc + __shfl_xor(lacc, 32, 64);
    if (hi == 0)
      lp[(size_t)bh * SEQ + q0 + wave * 32 + l31] = ltot;
  }

  // O-store: scatter o into LDS [128][64] (q-row major), then coalesced
  // full-line uint4 copy-out. C layout: row q = (r&3)+8*(r>>2)+4*hi, col d.
  __syncthreads();  // all waves done with K LDS
  ushort* Ob = &Kbuf[0][0];  // 16 KB region
#pragma unroll
  for (int r = 0; r < 16; ++r) {
    int row = wave * 32 + (r & 3) + 8 * (r >> 2) + 4 * hi;
    Ob[row * 64 + l31] = f2b(o0[r]);
    Ob[row * 64 + 32 + l31] = f2b(o1[r]);
  }
  __syncthreads();  // O tile visible
  {
    uint4* dst = (uint4*)(Op + ((size_t)bh * SEQ + q0) * 64);
    const uint4* src = (const uint4*)Ob;
#pragma unroll
    for (int i = 0; i < 4; ++i)
      dst[i * 256 + tid] = src[i * 256 + tid];
  }
}

// ctx = (O1+O2+O3+O4) / (l1+l2+l3+l4), routed to (B, T, D_MODEL) bf16
__global__ __launch_bounds__(256) void recombine(const ushort* __restrict__ O1,
                                                 const ushort* __restrict__ O2,
                                                 const ushort* __restrict__ O3,
                                                 const ushort* __restrict__ O4,
                                                 const float* __restrict__ l1,
                                                 const float* __restrict__ l2,
                                                 const float* __restrict__ l3,
                                                 const float* __restrict__ l4,
                                                 ushort* __restrict__ ctx) {
  int idx = blockIdx.x * 256 + threadIdx.x;   // over (BH*T*64)/8 uint4 chunks
  int row = idx >> 3;                         // bh*SEQ + t
  int d8 = idx & 7;
  uint4 a = ((const uint4*)O1)[idx];
  uint4 b = ((const uint4*)O2)[idx];
  uint4 c = ((const uint4*)O3)[idx];
  uint4 d = ((const uint4*)O4)[idx];
  float linv = 1.f / (((l1[row] + l2[row]) + (l3[row] + l4[row])));
  uint4 res;
  unsigned* ap = (unsigned*)&a;
  unsigned* bp = (unsigned*)&b;
  unsigned* cp = (unsigned*)&c;
  unsigned* dp = (unsigned*)&d;
  unsigned* rp = (unsigned*)&res;
#pragma unroll
  for (int i = 0; i < 4; ++i) {
    float lo = ((blo(ap[i]) + blo(bp[i])) + (blo(cp[i]) + blo(dp[i]))) * linv;
    float hi = ((bhi(ap[i]) + bhi(bp[i])) + (bhi(cp[i]) + bhi(dp[i]))) * linv;
    rp[i] = pk2(lo, hi);
  }
  int bh = row >> 11, t = row & 2047;
  int bb = bh >> 4, h = bh & 15;
  ((uint4*)ctx)[(size_t)(bb * SEQ + t) * 128 + h * 8 + d8] = res;
}

extern "C" void kernel_launch(void* const* d_in, const int* in_sizes, int n_in,
                              void* d_out, int out_size, void* d_ws, size_t ws_size,
                              hipStream_t stream) {
  const float* x  = (const float*)d_in[0];
  const float* Wq = (const float*)d_in[1];
  const float* Wk = (const float*)d_in[2];
  const float* Wv = (const float*)d_in[3];
  const float* Wo = (const float*)d_in[4];
  float* out = (float*)d_out;

  char* ws = (char*)d_ws;
  const size_t MB = 1 << 20;
  ushort* xb   = (ushort*)(ws);             // 8 MB (dead after gemm_qkv -> O2)
  ushort* wqkv = (ushort*)(ws +  8 * MB);   // 6 MB (dead after gemm_qkv -> l1..l4)
  ushort* wob  = (ushort*)(ws + 14 * MB);   // 2 MB (live until gemm_out)
  ushort* Qh   = (ushort*)(ws + 16 * MB);   // 8 MB (BH,T,64); dead after attn -> ctx
  ushort* Kh   = (ushort*)(ws + 24 * MB);   // 8 MB (BH,T,64)
  ushort* Vth  = (ushort*)(ws + 32 * MB);   // 8 MB (BH,64,T)
  ushort* ctxO = (ushort*)(ws + 40 * MB);   // 8 MB: O3 partial during attn

  // split-K partials (regions dead during attn):
  ushort* O1 = (ushort*)d_out;                       // out[0:8MB]
  ushort* O2 = xb;                                   // xb region
  ushort* O3 = ctxO;                                 // ws+40MB region
  ushort* O4 = (ushort*)d_out + (4u << 20);          // out[8MB:16MB]
  float*  l1 = (float*)wqkv;                         // 256 KB each
  float*  l2 = (float*)(ws + 8 * MB + 256 * 1024);
  float*  l3 = (float*)(ws + 8 * MB + 512 * 1024);
  float*  l4 = (float*)(ws + 8 * MB + 768 * 1024);
  // recombine output goes into the Qh region (dead after attn)
  ushort* ctx = Qh;

  cast_all<<<8192, 256, 0, stream>>>(x, Wq, Wk, Wv, Wo, xb, wqkv, wob);

  const float qscale = 0.125f * 1.44269504089f;  // SCALE * log2(e)
  gemm_qkv<<<dim3(3072 / 128, 4096 / 128), 256, 0, stream>>>(xb, wqkv, Qh, Kh, Vth, qscale);

  // 1D grid, 2048 blocks: id = qb*128 + (bh*4+quarter) -> id%8 fixed per stream
  attn_kernel<<<(SEQ / 128) * BATCH * N_HEADS * 4, 256, 0, stream>>>(
      Qh, Kh, Vth, O1, O2, O3, O4, l1, l2, l3, l4);

  recombine<<<(BATCH * N_HEADS * SEQ * 64 / 8) / 256, 256, 0, stream>>>(
      O1, O2, O3, O4, l1, l2, l3, l4, ctx);

  gemm_out<<<dim3(1024 / 128, 4096 / 64), 256, 0, stream>>>(ctx, wob, out);
}

// Round 9
// 194.693 us; speedup vs baseline: 1.1415x; 1.1415x over previous
//
#include <hip/hip_runtime.h>
#include <hip/hip_bf16.h>

#define D_MODEL 1024
#define N_HEADS 16
#define HEAD_DIM 64
#define SEQ 2048
#define BATCH 2

typedef __attribute__((ext_vector_type(8))) short bf16x8;
typedef __attribute__((ext_vector_type(4))) short bf16x4;
typedef __attribute__((ext_vector_type(4))) float f32x4;
typedef __attribute__((ext_vector_type(16))) float f32x16;

typedef __attribute__((address_space(3))) unsigned lds_uint;
typedef __attribute__((address_space(1))) const unsigned global_cuint;

__device__ __forceinline__ void async_cp16(const ushort* g, ushort* l) {
  __builtin_amdgcn_global_load_lds((global_cuint*)g, (lds_uint*)l, 16, 0, 0);
}

__device__ __forceinline__ ushort f2b(float f) {
  union { float f; unsigned u; } x; x.f = f;
  unsigned r = x.u + 0x7fffu + ((x.u >> 16) & 1u);
  return (ushort)(r >> 16);
}

// packed f32x2 -> bf16x2; low word = a
__device__ __forceinline__ unsigned pk2(float a, float b) {
  __hip_bfloat162 h = __float22bfloat162_rn(float2{a, b});
  union { __hip_bfloat162 h; unsigned u; } x; x.h = h;
  return x.u;
}

__device__ __forceinline__ float blo(unsigned u) {
  union { unsigned u; float f; } x; x.u = u << 16; return x.f;
}
__device__ __forceinline__ float bhi(unsigned u) {
  union { unsigned u; float f; } x; x.u = u & 0xffff0000u; return x.f;
}

// XOR-swizzled ushort index into a [64][64] (128 B/row) LDS tile.
// byte_off within row ^= (row&7)<<4. With pre-swizzled global staging
// (source 16B-slot = (l&7)^(l>>3)) the staging write is lane-linear and
// all b128 frag reads distribute exactly 8 lanes per 16B slot.
__device__ __forceinline__ int swz64(int row, int colbyte) {
  return row * 64 + ((colbyte ^ ((row & 7) << 4)) >> 1);
}

// Single fused cast: x (1M uint4) + Wq/Wk/Wv (-> wqkv) + Wo (-> wob).
__global__ __launch_bounds__(256) void cast_all(const float* __restrict__ x,
                                                const float* __restrict__ Wq,
                                                const float* __restrict__ Wk,
                                                const float* __restrict__ Wv,
                                                const float* __restrict__ Wo,
                                                ushort* __restrict__ xb,
                                                ushort* __restrict__ wqkv,
                                                ushort* __restrict__ wob) {
  int idx = blockIdx.x * 256 + threadIdx.x;  // 0 .. 2M-1 (uint4 units)
  const float* in;
  uint2* out;
  if (idx < (1 << 20)) {
    in = x; out = (uint2*)xb;
  } else {
    int j = idx - (1 << 20);
    int w = j >> 18;            // 0..3
    idx = j & 0x3FFFF;          // 256K uint4 per weight
    switch (w) {
      case 0: in = Wq; out = (uint2*)wqkv; break;
      case 1: in = Wk; out = (uint2*)(wqkv) + (1 << 18); break;
      case 2: in = Wv; out = (uint2*)(wqkv) + (2 << 18); break;
      default: in = Wo; out = (uint2*)wob; break;
    }
  }
  float4 v = ((const float4*)in)[idx];
  uint2 o; o.x = pk2(v.x, v.y); o.y = pk2(v.z, v.w);
  out[idx] = o;
}

// Fused QKV projection: A = xb (4096x1024 bf16), Bw = wqkv (3072x1024 bf16).
// 128x128 tile, BK=64 (16 K-iters). Dbuf LDS, 1 barrier/K-step, swizzled.
__global__ __launch_bounds__(256) void gemm_qkv(const ushort* __restrict__ A,
                                                const ushort* __restrict__ Bw,
                                                ushort* __restrict__ Qh,
                                                ushort* __restrict__ Kh,
                                                ushort* __restrict__ Vth,
                                                float qscale) {
  constexpr int K = 1024;
  const int bm = blockIdx.y * 128;
  const int bn = blockIdx.x * 128;
  const int tid = threadIdx.x;
  const int wave = tid >> 6;
  const int lane = tid & 63;
  const int l16 = lane & 15;
  const int quad = lane >> 4;

  __shared__ ushort As[2][128 * 64];   // 32 KB (dbuf)
  __shared__ ushort Bs[2][128 * 64];   // 32 KB (dbuf)

  const int wm = (wave & 1) * 64;
  const int wn = (wave >> 1) * 64;

  f32x4 acc[4][4];
#pragma unroll
  for (int r = 0; r < 4; ++r)
#pragma unroll
    for (int c = 0; c < 4; ++c) acc[r][c] = (f32x4){0.f, 0.f, 0.f, 0.f};

  const int srow = wave * 8 + (lane >> 3);
  const int csw = (((lane & 7) ^ (lane >> 3)) << 3);  // pre-swizzled col (ushorts)

  // prologue: tile 0 -> buf 0
#pragma unroll
  for (int j = 0; j < 4; ++j) {
    async_cp16(A  + (size_t)(bm + j * 32 + srow) * K + csw, &As[0][(j * 32 + wave * 8) * 64]);
    async_cp16(Bw + (size_t)(bn + j * 32 + srow) * K + csw, &Bs[0][(j * 32 + wave * 8) * 64]);
  }

  constexpr int NIT = K / 64;  // 16
  for (int kt = 0; kt < NIT; ++kt) {
    __syncthreads();  // vmcnt(0) drain: tile kt landed; prior reads of buf^1 done
    const int buf = kt & 1;
    if (kt + 1 < NIT) {
      const int k0 = (kt + 1) * 64;
#pragma unroll
      for (int j = 0; j < 4; ++j) {
        async_cp16(A  + (size_t)(bm + j * 32 + srow) * K + k0 + csw, &As[buf ^ 1][(j * 32 + wave * 8) * 64]);
        async_cp16(Bw + (size_t)(bn + j * 32 + srow) * K + k0 + csw, &Bs[buf ^ 1][(j * 32 + wave * 8) * 64]);
      }
    }

    bf16x8 a[2][4], b[2][4];
#pragma unroll
    for (int ks = 0; ks < 2; ++ks)
#pragma unroll
      for (int r = 0; r < 4; ++r) {
        a[ks][r] = *(const bf16x8*)(&As[buf][swz64(wm + r * 16 + l16, ks * 64 + quad * 16)]);
        b[ks][r] = *(const bf16x8*)(&Bs[buf][swz64(wn + r * 16 + l16, ks * 64 + quad * 16)]);
      }
#pragma unroll
    for (int ks = 0; ks < 2; ++ks)
#pragma unroll
      for (int r = 0; r < 4; ++r)
#pragma unroll
        for (int c = 0; c < 4; ++c)
          acc[r][c] = __builtin_amdgcn_mfma_f32_16x16x32_bf16(a[ks][r], b[ks][c], acc[r][c], 0, 0, 0);
  }

#pragma unroll
  for (int r = 0; r < 4; ++r) {
#pragma unroll
    for (int c = 0; c < 4; ++c) {
      int ncol = bn + wn + c * 16 + l16;   // 0..3071; w uniform per (block,wave)
      int w = ncol >> 10;
      int f = ncol & 1023;
      int h = f >> 6, d = f & 63;
      if (w == 2) {
        // V^T: 4 consecutive tokens per lane -> one b64 store
        int m0 = bm + wm + r * 16 + quad * 4;
        int b = m0 >> 11, t0 = m0 & 2047;
        uint2 pp;
        pp.x = pk2(acc[r][c][0], acc[r][c][1]);
        pp.y = pk2(acc[r][c][2], acc[r][c][3]);
        *(uint2*)(&Vth[((size_t)(b * 1024 + f) << 11) + t0]) = pp;
      } else {
#pragma unroll
        for (int rr = 0; rr < 4; ++rr) {
          float v = acc[r][c][rr];
          int m = bm + wm + r * 16 + quad * 4 + rr;
          int b = m >> 11, t = m & 2047;
          if (w == 0)
            Qh[((size_t)(b * 16 + h) * SEQ + t) * 64 + d] = f2b(v * qscale);
          else
            Kh[((size_t)(b * 16 + h) * SEQ + t) * 64 + d] = f2b(v);
        }
      }
    }
  }
}

// Output projection: A = ctx (4096x1024 bf16), Bw = wob, fp32 out.
// 64x128 tile, BK=64. Dbuf + swizzle (R15).
__global__ __launch_bounds__(256) void gemm_out(const ushort* __restrict__ A,
                                                const ushort* __restrict__ Bw,
                                                float* __restrict__ out) {
  constexpr int K = 1024;
  const int bm = blockIdx.y * 64;
  const int bn = blockIdx.x * 128;
  const int tid = threadIdx.x;
  const int wave = tid >> 6;
  const int lane = tid & 63;
  const int l16 = lane & 15;
  const int quad = lane >> 4;

  __shared__ ushort As[2][64 * 64];    // 16 KB (dbuf)
  __shared__ ushort Bs[2][128 * 64];   // 32 KB (dbuf)

  const int wm = (wave & 1) * 32;
  const int wn = (wave >> 1) * 64;

  f32x4 acc[2][4];
#pragma unroll
  for (int r = 0; r < 2; ++r)
#pragma unroll
    for (int c = 0; c < 4; ++c) acc[r][c] = (f32x4){0.f, 0.f, 0.f, 0.f};

  const int srow = wave * 8 + (lane >> 3);
  const int csw = (((lane & 7) ^ (lane >> 3)) << 3);  // pre-swizzled col (ushorts)

  // prologue: tile 0 -> buf 0
#pragma unroll
  for (int j = 0; j < 2; ++j)
    async_cp16(A + (size_t)(bm + j * 32 + srow) * K + csw, &As[0][(j * 32 + wave * 8) * 64]);
#pragma unroll
  for (int j = 0; j < 4; ++j)
    async_cp16(Bw + (size_t)(bn + j * 32 + srow) * K + csw, &Bs[0][(j * 32 + wave * 8) * 64]);

  constexpr int NIT = K / 64;  // 16
  for (int kt = 0; kt < NIT; ++kt) {
    __syncthreads();
    const int buf = kt & 1;
    if (kt + 1 < NIT) {
      const int k0 = (kt + 1) * 64;
#pragma unroll
      for (int j = 0; j < 2; ++j)
        async_cp16(A + (size_t)(bm + j * 32 + srow) * K + k0 + csw, &As[buf ^ 1][(j * 32 + wave * 8) * 64]);
#pragma unroll
      for (int j = 0; j < 4; ++j)
        async_cp16(Bw + (size_t)(bn + j * 32 + srow) * K + k0 + csw, &Bs[buf ^ 1][(j * 32 + wave * 8) * 64]);
    }

    bf16x8 a[2][2], b[2][4];
#pragma unroll
    for (int ks = 0; ks < 2; ++ks) {
#pragma unroll
      for (int r = 0; r < 2; ++r)
        a[ks][r] = *(const bf16x8*)(&As[buf][swz64(wm + r * 16 + l16, ks * 64 + quad * 16)]);
#pragma unroll
      for (int c = 0; c < 4; ++c)
        b[ks][c] = *(const bf16x8*)(&Bs[buf][swz64(wn + c * 16 + l16, ks * 64 + quad * 16)]);
    }
#pragma unroll
    for (int ks = 0; ks < 2; ++ks)
#pragma unroll
      for (int r = 0; r < 2; ++r)
#pragma unroll
        for (int c = 0; c < 4; ++c)
          acc[r][c] = __builtin_amdgcn_mfma_f32_16x16x32_bf16(a[ks][r], b[ks][c], acc[r][c], 0, 0, 0);
  }

#pragma unroll
  for (int r = 0; r < 2; ++r)
#pragma unroll
    for (int c = 0; c < 4; ++c)
#pragma unroll
      for (int rr = 0; rr < 4; ++rr) {
        int m = bm + wm + r * 16 + quad * 4 + rr;
        int n = bn + wn + c * 16 + l16;
        out[(size_t)m * D_MODEL + n] = acc[r][c][rr];
      }
}

// Flash attention, R20: R17 structure (2-way K-split, 32 KB K/V dbuf staged
// by global_load_lds, 32x32x16 QK^T, in-register softmax) + ZERO-SHUFFLE PV.
// R19 post-mortem: V-from-global was 64-lines-per-instruction uncoalesced ->
// reverted to LDS staging. New: PV uses mfma_f32_32x32x8 whose A-operand
// layout (row = lane&31, k = 4*hi + j) matches the S^T C-layout natively:
// window w's A-frag = pk2(e[4w],e[4w+1]), pk2(e[4w+2],e[4w+3]) - consecutive
// registers, NO cross-lane exchange (removes 4 ds_bpermute + 24 selects per
// 32-key chunk and the serial shfl latency in the MFMA->MFMA chain). V frags
// are b64 LDS reads at the bank-bandwidth minimum (derived: hi-halves cover
// disjoint bank pairs, 4 words/bank). Falls back to the verified R17
// exchange if the 32x32x8 builtin is unavailable.
#if __has_builtin(__builtin_amdgcn_mfma_f32_32x32x8bf16_1k)
#define PV_ZERO_SHUFFLE 1
#endif
__global__ __launch_bounds__(256, 2) void attn_kernel(const ushort* __restrict__ Qh,
                                                      const ushort* __restrict__ Kh,
                                                      const ushort* __restrict__ Vth,
                                                      ushort* __restrict__ O1,
                                                      ushort* __restrict__ O2,
                                                      float* __restrict__ l1,
                                                      float* __restrict__ l2) {
  const int id = blockIdx.x;
  const int stream = id & 63;       // bh*2 + half
  const int qb = id >> 6;           // 0..15
  const int bh = stream >> 1;
  const int half = stream & 1;
  const int q0 = qb * 128;
  ushort* __restrict__ Op = half ? O2 : O1;
  float* __restrict__ lp = half ? l2 : l1;

  const int tid = threadIdx.x;
  const int wave = tid >> 6;
  const int lane = tid & 63;
  const int l31 = lane & 31;
  const int hi = lane >> 5;

  __shared__ ushort KVbuf[2][2][64 * 64];  // 32 KB: [buf][0=K,1=V^T], swizzled

  // Q frags (B-op of QK): col = l31 = q, k = d = dc*16 + hi*8 + j
  bf16x8 qf[4];
#pragma unroll
  for (int dc = 0; dc < 4; ++dc)
    qf[dc] = *(const bf16x8*)(Qh + ((size_t)bh * SEQ + q0 + wave * 32 + l31) * 64 + dc * 16 + hi * 8);

  f32x16 o0 = {0.f, 0.f, 0.f, 0.f, 0.f, 0.f, 0.f, 0.f,
               0.f, 0.f, 0.f, 0.f, 0.f, 0.f, 0.f, 0.f};
  f32x16 o1 = o0;
  float lacc = 0.f;

  // async staging geometry: wave fills chunks {2w,2w+1} (8 rows each);
  // source 16B-slot pre-swizzled so the lane-linear LDS write leaves data
  // at the swz64 position.
  const int chunk = wave * 2;
  const int r8 = lane >> 3;
  const int csw = (((lane & 7) ^ r8) << 3);   // ushort offset within 64
  const ushort* kbase = Kh + ((size_t)bh * SEQ + half * 1024) * 64;
  const ushort* vbase = Vth + (size_t)bh * 64 * SEQ + half * 1024;
  const ushort* ksrc = kbase + (size_t)(chunk * 8 + r8) * 64 + csw;   // +kt*4096
  const ushort* vsrc = vbase + (size_t)(chunk * 8 + r8) * SEQ + csw;  // +kt*64

  // prologue: tile 0 -> buf 0
  async_cp16(ksrc,           &KVbuf[0][0][chunk * 512]);
  async_cp16(ksrc + 8 * 64,  &KVbuf[0][0][(chunk + 1) * 512]);
  async_cp16(vsrc,           &KVbuf[0][1][chunk * 512]);
  async_cp16(vsrc + 8 * SEQ, &KVbuf[0][1][(chunk + 1) * 512]);

  constexpr int NIT = 1024 / 64;  // 16
  for (int kt = 0; kt < NIT; ++kt) {
    __syncthreads();  // drains vmcnt: tile kt landed; prior reads of buf^1 done
    const int buf = kt & 1;
    if (kt + 1 < NIT) {
      const ushort* ks = ksrc + (size_t)(kt + 1) * 64 * 64;
      const ushort* vs = vsrc + (kt + 1) * 64;
      async_cp16(ks,           &KVbuf[buf ^ 1][0][chunk * 512]);
      async_cp16(ks + 8 * 64,  &KVbuf[buf ^ 1][0][(chunk + 1) * 512]);
      async_cp16(vs,           &KVbuf[buf ^ 1][1][chunk * 512]);
      async_cp16(vs + 8 * SEQ, &KVbuf[buf ^ 1][1][(chunk + 1) * 512]);
    }
    const ushort* Kt = KVbuf[buf][0];
    const ushort* Vt = KVbuf[buf][1];

#pragma unroll
    for (int kt2 = 0; kt2 < 2; ++kt2) {
      // QK^T: A = K (row = key = kt2*32 + l31, k = d), 4 d-chunks
      bf16x8 ka0 = *(const bf16x8*)(&Kt[swz64(kt2 * 32 + l31, 0 * 32 + hi * 16)]);
      bf16x8 ka1 = *(const bf16x8*)(&Kt[swz64(kt2 * 32 + l31, 1 * 32 + hi * 16)]);
      bf16x8 ka2 = *(const bf16x8*)(&Kt[swz64(kt2 * 32 + l31, 2 * 32 + hi * 16)]);
      bf16x8 ka3 = *(const bf16x8*)(&Kt[swz64(kt2 * 32 + l31, 3 * 32 + hi * 16)]);
      f32x16 z = {0.f, 0.f, 0.f, 0.f, 0.f, 0.f, 0.f, 0.f,
                  0.f, 0.f, 0.f, 0.f, 0.f, 0.f, 0.f, 0.f};
      z = __builtin_amdgcn_mfma_f32_32x32x16_bf16(ka0, qf[0], z, 0, 0, 0);
      z = __builtin_amdgcn_mfma_f32_32x32x16_bf16(ka1, qf[1], z, 0, 0, 0);
      z = __builtin_amdgcn_mfma_f32_32x32x16_bf16(ka2, qf[2], z, 0, 0, 0);
      z = __builtin_amdgcn_mfma_f32_32x32x16_bf16(ka3, qf[3], z, 0, 0, 0);

      float e[16];
#pragma unroll
      for (int r = 0; r < 16; ++r) e[r] = __builtin_amdgcn_exp2f(z[r]);
      lacc += (((e[0] + e[1]) + (e[2] + e[3])) + ((e[4] + e[5]) + (e[6] + e[7])))
            + (((e[8] + e[9]) + (e[10] + e[11])) + ((e[12] + e[13]) + (e[14] + e[15])));

#if PV_ZERO_SHUFFLE
      // e[4w+j] holds key kt2*32 + w*8 + 4*hi + j for this lane's q = l31:
      // exactly the 32x32x8 A-operand (row = l31, k = 4*hi + j). V B-frag:
      // b64 at V^T[d][kt2*32 + w*8 + 4*hi] (col = d, k = 4*hi + j).
#pragma unroll
      for (int w = 0; w < 4; ++w) {
        union { unsigned u[2]; bf16x4 v; } pu;
        pu.u[0] = pk2(e[4 * w + 0], e[4 * w + 1]);
        pu.u[1] = pk2(e[4 * w + 2], e[4 * w + 3]);
        const int cb = kt2 * 64 + w * 16 + hi * 8;  // byte col in V^T row
        bf16x4 vb0 = *(const bf16x4*)(&Vt[swz64(l31, cb)]);
        bf16x4 vb1 = *(const bf16x4*)(&Vt[swz64(32 + l31, cb)]);
        o0 = __builtin_amdgcn_mfma_f32_32x32x8bf16_1k(pu.v, vb0, o0, 0, 0, 0);
        o1 = __builtin_amdgcn_mfma_f32_32x32x8bf16_1k(pu.v, vb1, o1, 0, 0, 0);
      }
#else
#pragma unroll
      for (int lw = 0; lw < 2; ++lw) {
        const int base = lw * 8;
        unsigned pa0 = pk2(e[base + 0], e[base + 1]);
        unsigned pa1 = pk2(e[base + 2], e[base + 3]);
        unsigned pa2 = pk2(e[base + 4], e[base + 5]);
        unsigned pa3 = pk2(e[base + 6], e[base + 7]);
        // cross-half exchange: hi=0's (pa2,pa3) <-> hi=1's (pa0,pa1).
        unsigned s0 = hi ? pa0 : pa2;
        unsigned s1 = hi ? pa1 : pa3;
        unsigned t0 = __shfl_xor(s0, 32, 64);
        unsigned t1 = __shfl_xor(s1, 32, 64);
        pa2 = hi ? pa2 : t0;
        pa3 = hi ? pa3 : t1;
        pa0 = hi ? t0 : pa0;
        pa1 = hi ? t1 : pa1;
        union { unsigned u[4]; bf16x8 v; } pu;
        pu.u[0] = pa0; pu.u[1] = pa1; pu.u[2] = pa2; pu.u[3] = pa3;
        const int wb = (kt2 * 2 + lw) * 32;  // window byte col in V^T
        bf16x8 vb0 = *(const bf16x8*)(&Vt[swz64(0 + l31, wb + hi * 16)]);
        bf16x8 vb1 = *(const bf16x8*)(&Vt[swz64(32 + l31, wb + hi * 16)]);
        o0 = __builtin_amdgcn_mfma_f32_32x32x16_bf16(pu.v, vb0, o0, 0, 0, 0);
        o1 = __builtin_amdgcn_mfma_f32_32x32x16_bf16(pu.v, vb1, o1, 0, 0, 0);
      }
#endif
    }
  }

  // l: lane and lane+32 hold complementary key-halves of the same q = l31.
  {
    float ltot = lacc + __shfl_xor(lacc, 32, 64);
    if (hi == 0)
      lp[(size_t)bh * SEQ + q0 + wave * 32 + l31] = ltot;
  }

  // O-store: scatter o into LDS [128][64] (q-row major), then coalesced
  // full-line uint4 copy-out. C layout: row q = (r&3)+8*(r>>2)+4*hi, col d.
  __syncthreads();  // all waves done with K/V LDS
  ushort* Ob = &KVbuf[0][0][0];  // 16 KB region
#pragma unroll
  for (int r = 0; r < 16; ++r) {
    int row = wave * 32 + (r & 3) + 8 * (r >> 2) + 4 * hi;
    Ob[row * 64 + l31] = f2b(o0[r]);
    Ob[row * 64 + 32 + l31] = f2b(o1[r]);
  }
  __syncthreads();  // O tile visible
  {
    uint4* dst = (uint4*)(Op + ((size_t)bh * SEQ + q0) * 64);
    const uint4* src = (const uint4*)Ob;
#pragma unroll
    for (int i = 0; i < 4; ++i)
      dst[i * 256 + tid] = src[i * 256 + tid];
  }
}

// ctx = (O1 + O2) / (l1 + l2), routed to (B, T, D_MODEL) bf16
__global__ __launch_bounds__(256) void recombine(const ushort* __restrict__ O1,
                                                 const ushort* __restrict__ O2,
                                                 const float* __restrict__ l1,
                                                 const float* __restrict__ l2,
                                                 ushort* __restrict__ ctx) {
  int idx = blockIdx.x * 256 + threadIdx.x;   // over (BH*T*64)/8 uint4 chunks
  int row = idx >> 3;                         // bh*SEQ + t
  int d8 = idx & 7;
  uint4 a = ((const uint4*)O1)[idx];
  uint4 b = ((const uint4*)O2)[idx];
  float linv = 1.f / (l1[row] + l2[row]);
  uint4 res;
  unsigned* ap = (unsigned*)&a;
  unsigned* bp = (unsigned*)&b;
  unsigned* rp = (unsigned*)&res;
#pragma unroll
  for (int i = 0; i < 4; ++i) {
    float lo = (blo(ap[i]) + blo(bp[i])) * linv;
    float hi = (bhi(ap[i]) + bhi(bp[i])) * linv;
    rp[i] = pk2(lo, hi);
  }
  int bh = row >> 11, t = row & 2047;
  int bb = bh >> 4, h = bh & 15;
  ((uint4*)ctx)[(size_t)(bb * SEQ + t) * 128 + h * 8 + d8] = res;
}

extern "C" void kernel_launch(void* const* d_in, const int* in_sizes, int n_in,
                              void* d_out, int out_size, void* d_ws, size_t ws_size,
                              hipStream_t stream) {
  const float* x  = (const float*)d_in[0];
  const float* Wq = (const float*)d_in[1];
  const float* Wk = (const float*)d_in[2];
  const float* Wv = (const float*)d_in[3];
  const float* Wo = (const float*)d_in[4];
  float* out = (float*)d_out;

  char* ws = (char*)d_ws;
  const size_t MB = 1 << 20;
  ushort* xb   = (ushort*)(ws);             // 8 MB (dead after gemm_qkv -> O2)
  ushort* wqkv = (ushort*)(ws +  8 * MB);   // 6 MB (dead after gemm_qkv -> l1/l2)
  ushort* wob  = (ushort*)(ws + 14 * MB);   // 2 MB (live until gemm_out)
  ushort* Qh   = (ushort*)(ws + 16 * MB);   // 8 MB (BH,T,64)
  ushort* Kh   = (ushort*)(ws + 24 * MB);   // 8 MB (BH,T,64)
  ushort* Vth  = (ushort*)(ws + 32 * MB);   // 8 MB (BH,64,T)
  ushort* ctx  = (ushort*)(ws + 40 * MB);   // 8 MB (B,T,D)

  // split-K partials (regions dead during attn):
  ushort* O1 = (ushort*)d_out;              // 8 MB of the 16 MB output buffer
  ushort* O2 = xb;                          // xb region, dead after gemm_qkv
  float*  l1 = (float*)wqkv;                // 256 KB
  float*  l2 = (float*)(ws + 8 * MB + 256 * 1024);

  cast_all<<<8192, 256, 0, stream>>>(x, Wq, Wk, Wv, Wo, xb, wqkv, wob);

  const float qscale = 0.125f * 1.44269504089f;  // SCALE * log2(e)
  gemm_qkv<<<dim3(3072 / 128, 4096 / 128), 256, 0, stream>>>(xb, wqkv, Qh, Kh, Vth, qscale);

  // 1D grid, 1024 blocks: id = qb*64 + (bh*2+half) -> id%8 fixed per stream
  attn_kernel<<<(SEQ / 128) * BATCH * N_HEADS * 2, 256, 0, stream>>>(
      Qh, Kh, Vth, O1, O2, l1, l2);

  recombine<<<(BATCH * N_HEADS * SEQ * 64 / 8) / 256, 256, 0, stream>>>(O1, O2, l1, l2, ctx);

  gemm_out<<<dim3(1024 / 128, 4096 / 64), 256, 0, stream>>>(ctx, wob, out);
}

// Round 12
// 192.812 us; speedup vs baseline: 1.1526x; 1.0098x over previous
//
#include <hip/hip_runtime.h>
#include <hip/hip_bf16.h>

#define D_MODEL 1024
#define N_HEADS 16
#define HEAD_DIM 64
#define SEQ 2048
#define BATCH 2

typedef __attribute__((ext_vector_type(8))) short bf16x8;
typedef __attribute__((ext_vector_type(4))) short bf16x4;
typedef __attribute__((ext_vector_type(4))) float f32x4;
typedef __attribute__((ext_vector_type(16))) float f32x16;

typedef __attribute__((address_space(3))) unsigned lds_uint;
typedef __attribute__((address_space(1))) const unsigned global_cuint;

__device__ __forceinline__ void async_cp16(const ushort* g, ushort* l) {
  __builtin_amdgcn_global_load_lds((global_cuint*)g, (lds_uint*)l, 16, 0, 0);
}

__device__ __forceinline__ ushort f2b(float f) {
  union { float f; unsigned u; } x; x.f = f;
  unsigned r = x.u + 0x7fffu + ((x.u >> 16) & 1u);
  return (ushort)(r >> 16);
}

// packed f32x2 -> bf16x2; low word = a
__device__ __forceinline__ unsigned pk2(float a, float b) {
  __hip_bfloat162 h = __float22bfloat162_rn(float2{a, b});
  union { __hip_bfloat162 h; unsigned u; } x; x.h = h;
  return x.u;
}

__device__ __forceinline__ float blo(unsigned u) {
  union { unsigned u; float f; } x; x.u = u << 16; return x.f;
}
__device__ __forceinline__ float bhi(unsigned u) {
  union { unsigned u; float f; } x; x.u = u & 0xffff0000u; return x.f;
}

// XOR-swizzled ushort index into a [64][64] (128 B/row) LDS tile.
// byte_off within row ^= (row&7)<<4. With pre-swizzled global staging
// (source 16B-slot = (l&7)^(l>>3)) the staging write is lane-linear and
// all b128 frag reads distribute exactly 8 lanes per 16B slot.
__device__ __forceinline__ int swz64(int row, int colbyte) {
  return row * 64 + ((colbyte ^ ((row & 7) << 4)) >> 1);
}

// Single fused cast: x (1M uint4) + Wq/Wk/Wv (-> wqkv) + Wo (-> wob).
__global__ __launch_bounds__(256) void cast_all(const float* __restrict__ x,
                                                const float* __restrict__ Wq,
                                                const float* __restrict__ Wk,
                                                const float* __restrict__ Wv,
                                                const float* __restrict__ Wo,
                                                ushort* __restrict__ xb,
                                                ushort* __restrict__ wqkv,
                                                ushort* __restrict__ wob) {
  int idx = blockIdx.x * 256 + threadIdx.x;  // 0 .. 2M-1 (uint4 units)
  const float* in;
  uint2* out;
  if (idx < (1 << 20)) {
    in = x; out = (uint2*)xb;
  } else {
    int j = idx - (1 << 20);
    int w = j >> 18;            // 0..3
    idx = j & 0x3FFFF;          // 256K uint4 per weight
    switch (w) {
      case 0: in = Wq; out = (uint2*)wqkv; break;
      case 1: in = Wk; out = (uint2*)(wqkv) + (1 << 18); break;
      case 2: in = Wv; out = (uint2*)(wqkv) + (2 << 18); break;
      default: in = Wo; out = (uint2*)wob; break;
    }
  }
  float4 v = ((const float4*)in)[idx];
  uint2 o; o.x = pk2(v.x, v.y); o.y = pk2(v.z, v.w);
  out[idx] = o;
}

// Fused QKV projection: A = xb (4096x1024 bf16), Bw = wqkv (3072x1024 bf16).
// 128x128 tile, BK=64. R23 (= R21 with relaxed reg budget): 512-thread
// blocks (8 waves, 2Mx4N wave grid, 64x32 wave tile). LDS is per-block, so
// doubling threads doubles waves/CU at the same 64 KB dbuf: 2 blocks/CU ->
// 16 waves/CU (was 8 with 256 thr). launch_bounds (512,2): 256-reg budget,
// natural allocation ~75-90 regs stays <=128 so residency remains LDS-capped
// at 2 blocks/CU; no forced cap -> no allocator pressure, no spill risk.
// Dbuf 1-barrier structure + swizzle (R15, conflicts measured 0) retained.
// n<1024 -> Q (scaled), <2048 -> K, else -> V^T (packed b64 stores along t).
__global__ __launch_bounds__(512, 2) void gemm_qkv(const ushort* __restrict__ A,
                                                   const ushort* __restrict__ Bw,
                                                   ushort* __restrict__ Qh,
                                                   ushort* __restrict__ Kh,
                                                   ushort* __restrict__ Vth,
                                                   float qscale) {
  constexpr int K = 1024;
  const int bm = blockIdx.y * 128;
  const int bn = blockIdx.x * 128;
  const int tid = threadIdx.x;        // 0..511
  const int wave = tid >> 6;          // 0..7
  const int lane = tid & 63;
  const int l16 = lane & 15;
  const int quad = lane >> 4;

  __shared__ ushort As[2][128 * 64];   // 32 KB (dbuf)
  __shared__ ushort Bs[2][128 * 64];   // 32 KB (dbuf)

  const int wm = (wave & 1) * 64;      // 2 M-waves
  const int wn = (wave >> 1) * 32;     // 4 N-waves

  f32x4 acc[4][2];
#pragma unroll
  for (int r = 0; r < 4; ++r)
#pragma unroll
    for (int c = 0; c < 2; ++c) acc[r][c] = (f32x4){0.f, 0.f, 0.f, 0.f};

  // staging: per instruction round, 512 lanes x 16B = 64 rows x 128B.
  // wave w covers rows j*64 + w*8 + (lane>>3); LDS base is wave-uniform.
  const int srow = wave * 8 + (lane >> 3);            // 0..63
  const int csw = (((lane & 7) ^ (lane >> 3)) << 3);  // pre-swizzled col (ushorts)

  // prologue: tile 0 -> buf 0
#pragma unroll
  for (int j = 0; j < 2; ++j) {
    async_cp16(A  + (size_t)(bm + j * 64 + srow) * K + csw, &As[0][(j * 64 + wave * 8) * 64]);
    async_cp16(Bw + (size_t)(bn + j * 64 + srow) * K + csw, &Bs[0][(j * 64 + wave * 8) * 64]);
  }

  constexpr int NIT = K / 64;  // 16
  for (int kt = 0; kt < NIT; ++kt) {
    __syncthreads();  // vmcnt(0) drain: tile kt landed; prior reads of buf^1 done
    const int buf = kt & 1;
    if (kt + 1 < NIT) {
      const int k0 = (kt + 1) * 64;
#pragma unroll
      for (int j = 0; j < 2; ++j) {
        async_cp16(A  + (size_t)(bm + j * 64 + srow) * K + k0 + csw, &As[buf ^ 1][(j * 64 + wave * 8) * 64]);
        async_cp16(Bw + (size_t)(bn + j * 64 + srow) * K + k0 + csw, &Bs[buf ^ 1][(j * 64 + wave * 8) * 64]);
      }
    }

    bf16x8 a[2][4], b[2][2];
#pragma unroll
    for (int ks = 0; ks < 2; ++ks) {
#pragma unroll
      for (int r = 0; r < 4; ++r)
        a[ks][r] = *(const bf16x8*)(&As[buf][swz64(wm + r * 16 + l16, ks * 64 + quad * 16)]);
#pragma unroll
      for (int c = 0; c < 2; ++c)
        b[ks][c] = *(const bf16x8*)(&Bs[buf][swz64(wn + c * 16 + l16, ks * 64 + quad * 16)]);
    }
#pragma unroll
    for (int ks = 0; ks < 2; ++ks)
#pragma unroll
      for (int r = 0; r < 4; ++r)
#pragma unroll
        for (int c = 0; c < 2; ++c)
          acc[r][c] = __builtin_amdgcn_mfma_f32_16x16x32_bf16(a[ks][r], b[ks][c], acc[r][c], 0, 0, 0);
  }

#pragma unroll
  for (int r = 0; r < 4; ++r) {
#pragma unroll
    for (int c = 0; c < 2; ++c) {
      int ncol = bn + wn + c * 16 + l16;   // w uniform per (block,wave,c)
      int w = ncol >> 10;
      int f = ncol & 1023;
      int h = f >> 6, d = f & 63;
      if (w == 2) {
        // V^T: 4 consecutive tokens per lane -> one b64 store
        int m0 = bm + wm + r * 16 + quad * 4;
        int b = m0 >> 11, t0 = m0 & 2047;
        uint2 pp;
        pp.x = pk2(acc[r][c][0], acc[r][c][1]);
        pp.y = pk2(acc[r][c][2], acc[r][c][3]);
        *(uint2*)(&Vth[((size_t)(b * 1024 + f) << 11) + t0]) = pp;
      } else {
#pragma unroll
        for (int rr = 0; rr < 4; ++rr) {
          float v = acc[r][c][rr];
          int m = bm + wm + r * 16 + quad * 4 + rr;
          int b = m >> 11, t = m & 2047;
          if (w == 0)
            Qh[((size_t)(b * 16 + h) * SEQ + t) * 64 + d] = f2b(v * qscale);
          else
            Kh[((size_t)(b * 16 + h) * SEQ + t) * 64 + d] = f2b(v);
        }
      }
    }
  }
}

// Output projection: A = ctx (4096x1024 bf16), Bw = wob, fp32 out.
// 64x128 tile, BK=64. Dbuf + swizzle (R15).
__global__ __launch_bounds__(256) void gemm_out(const ushort* __restrict__ A,
                                                const ushort* __restrict__ Bw,
                                                float* __restrict__ out) {
  constexpr int K = 1024;
  const int bm = blockIdx.y * 64;
  const int bn = blockIdx.x * 128;
  const int tid = threadIdx.x;
  const int wave = tid >> 6;
  const int lane = tid & 63;
  const int l16 = lane & 15;
  const int quad = lane >> 4;

  __shared__ ushort As[2][64 * 64];    // 16 KB (dbuf)
  __shared__ ushort Bs[2][128 * 64];   // 32 KB (dbuf)

  const int wm = (wave & 1) * 32;
  const int wn = (wave >> 1) * 64;

  f32x4 acc[2][4];
#pragma unroll
  for (int r = 0; r < 2; ++r)
#pragma unroll
    for (int c = 0; c < 4; ++c) acc[r][c] = (f32x4){0.f, 0.f, 0.f, 0.f};

  const int srow = wave * 8 + (lane >> 3);
  const int csw = (((lane & 7) ^ (lane >> 3)) << 3);  // pre-swizzled col (ushorts)

  // prologue: tile 0 -> buf 0
#pragma unroll
  for (int j = 0; j < 2; ++j)
    async_cp16(A + (size_t)(bm + j * 32 + srow) * K + csw, &As[0][(j * 32 + wave * 8) * 64]);
#pragma unroll
  for (int j = 0; j < 4; ++j)
    async_cp16(Bw + (size_t)(bn + j * 32 + srow) * K + csw, &Bs[0][(j * 32 + wave * 8) * 64]);

  constexpr int NIT = K / 64;  // 16
  for (int kt = 0; kt < NIT; ++kt) {
    __syncthreads();
    const int buf = kt & 1;
    if (kt + 1 < NIT) {
      const int k0 = (kt + 1) * 64;
#pragma unroll
      for (int j = 0; j < 2; ++j)
        async_cp16(A + (size_t)(bm + j * 32 + srow) * K + k0 + csw, &As[buf ^ 1][(j * 32 + wave * 8) * 64]);
#pragma unroll
      for (int j = 0; j < 4; ++j)
        async_cp16(Bw + (size_t)(bn + j * 32 + srow) * K + k0 + csw, &Bs[buf ^ 1][(j * 32 + wave * 8) * 64]);
    }

    bf16x8 a[2][2], b[2][4];
#pragma unroll
    for (int ks = 0; ks < 2; ++ks) {
#pragma unroll
      for (int r = 0; r < 2; ++r)
        a[ks][r] = *(const bf16x8*)(&As[buf][swz64(wm + r * 16 + l16, ks * 64 + quad * 16)]);
#pragma unroll
      for (int c = 0; c < 4; ++c)
        b[ks][c] = *(const bf16x8*)(&Bs[buf][swz64(wn + c * 16 + l16, ks * 64 + quad * 16)]);
    }
#pragma unroll
    for (int ks = 0; ks < 2; ++ks)
#pragma unroll
      for (int r = 0; r < 2; ++r)
#pragma unroll
        for (int c = 0; c < 4; ++c)
          acc[r][c] = __builtin_amdgcn_mfma_f32_16x16x32_bf16(a[ks][r], b[ks][c], acc[r][c], 0, 0, 0);
  }

#pragma unroll
  for (int r = 0; r < 2; ++r)
#pragma unroll
    for (int c = 0; c < 4; ++c)
#pragma unroll
      for (int rr = 0; rr < 4; ++rr) {
        int m = bm + wm + r * 16 + quad * 4 + rr;
        int n = bn + wn + c * 16 + l16;
        out[(size_t)m * D_MODEL + n] = acc[r][c][rr];
      }
}

// Flash attention, R20 (unchanged): 2-way K-split, 32 KB K/V dbuf staged by
// global_load_lds, 32x32x16 QK^T, in-register softmax, and ZERO-SHUFFLE PV
// via mfma_f32_32x32x8bf16_1k (A-operand k = 4*hi + j matches the S^T
// C-layout natively; no cross-lane exchange).
#if __has_builtin(__builtin_amdgcn_mfma_f32_32x32x8bf16_1k)
#define PV_ZERO_SHUFFLE 1
#endif
__global__ __launch_bounds__(256, 2) void attn_kernel(const ushort* __restrict__ Qh,
                                                      const ushort* __restrict__ Kh,
                                                      const ushort* __restrict__ Vth,
                                                      ushort* __restrict__ O1,
                                                      ushort* __restrict__ O2,
                                                      float* __restrict__ l1,
                                                      float* __restrict__ l2) {
  const int id = blockIdx.x;
  const int stream = id & 63;       // bh*2 + half
  const int qb = id >> 6;           // 0..15
  const int bh = stream >> 1;
  const int half = stream & 1;
  const int q0 = qb * 128;
  ushort* __restrict__ Op = half ? O2 : O1;
  float* __restrict__ lp = half ? l2 : l1;

  const int tid = threadIdx.x;
  const int wave = tid >> 6;
  const int lane = tid & 63;
  const int l31 = lane & 31;
  const int hi = lane >> 5;

  __shared__ ushort KVbuf[2][2][64 * 64];  // 32 KB: [buf][0=K,1=V^T], swizzled

  // Q frags (B-op of QK): col = l31 = q, k = d = dc*16 + hi*8 + j
  bf16x8 qf[4];
#pragma unroll
  for (int dc = 0; dc < 4; ++dc)
    qf[dc] = *(const bf16x8*)(Qh + ((size_t)bh * SEQ + q0 + wave * 32 + l31) * 64 + dc * 16 + hi * 8);

  f32x16 o0 = {0.f, 0.f, 0.f, 0.f, 0.f, 0.f, 0.f, 0.f,
               0.f, 0.f, 0.f, 0.f, 0.f, 0.f, 0.f, 0.f};
  f32x16 o1 = o0;
  float lacc = 0.f;

  // async staging geometry: wave fills chunks {2w,2w+1} (8 rows each);
  // source 16B-slot pre-swizzled so the lane-linear LDS write leaves data
  // at the swz64 position.
  const int chunk = wave * 2;
  const int r8 = lane >> 3;
  const int csw = (((lane & 7) ^ r8) << 3);   // ushort offset within 64
  const ushort* kbase = Kh + ((size_t)bh * SEQ + half * 1024) * 64;
  const ushort* vbase = Vth + (size_t)bh * 64 * SEQ + half * 1024;
  const ushort* ksrc = kbase + (size_t)(chunk * 8 + r8) * 64 + csw;   // +kt*4096
  const ushort* vsrc = vbase + (size_t)(chunk * 8 + r8) * SEQ + csw;  // +kt*64

  // prologue: tile 0 -> buf 0
  async_cp16(ksrc,           &KVbuf[0][0][chunk * 512]);
  async_cp16(ksrc + 8 * 64,  &KVbuf[0][0][(chunk + 1) * 512]);
  async_cp16(vsrc,           &KVbuf[0][1][chunk * 512]);
  async_cp16(vsrc + 8 * SEQ, &KVbuf[0][1][(chunk + 1) * 512]);

  constexpr int NIT = 1024 / 64;  // 16
  for (int kt = 0; kt < NIT; ++kt) {
    __syncthreads();  // drains vmcnt: tile kt landed; prior reads of buf^1 done
    const int buf = kt & 1;
    if (kt + 1 < NIT) {
      const ushort* ks = ksrc + (size_t)(kt + 1) * 64 * 64;
      const ushort* vs = vsrc + (kt + 1) * 64;
      async_cp16(ks,           &KVbuf[buf ^ 1][0][chunk * 512]);
      async_cp16(ks + 8 * 64,  &KVbuf[buf ^ 1][0][(chunk + 1) * 512]);
      async_cp16(vs,           &KVbuf[buf ^ 1][1][chunk * 512]);
      async_cp16(vs + 8 * SEQ, &KVbuf[buf ^ 1][1][(chunk + 1) * 512]);
    }
    const ushort* Kt = KVbuf[buf][0];
    const ushort* Vt = KVbuf[buf][1];

#pragma unroll
    for (int kt2 = 0; kt2 < 2; ++kt2) {
      // QK^T: A = K (row = key = kt2*32 + l31, k = d), 4 d-chunks
      bf16x8 ka0 = *(const bf16x8*)(&Kt[swz64(kt2 * 32 + l31, 0 * 32 + hi * 16)]);
      bf16x8 ka1 = *(const bf16x8*)(&Kt[swz64(kt2 * 32 + l31, 1 * 32 + hi * 16)]);
      bf16x8 ka2 = *(const bf16x8*)(&Kt[swz64(kt2 * 32 + l31, 2 * 32 + hi * 16)]);
      bf16x8 ka3 = *(const bf16x8*)(&Kt[swz64(kt2 * 32 + l31, 3 * 32 + hi * 16)]);
      f32x16 z = {0.f, 0.f, 0.f, 0.f, 0.f, 0.f, 0.f, 0.f,
                  0.f, 0.f, 0.f, 0.f, 0.f, 0.f, 0.f, 0.f};
      z = __builtin_amdgcn_mfma_f32_32x32x16_bf16(ka0, qf[0], z, 0, 0, 0);
      z = __builtin_amdgcn_mfma_f32_32x32x16_bf16(ka1, qf[1], z, 0, 0, 0);
      z = __builtin_amdgcn_mfma_f32_32x32x16_bf16(ka2, qf[2], z, 0, 0, 0);
      z = __builtin_amdgcn_mfma_f32_32x32x16_bf16(ka3, qf[3], z, 0, 0, 0);

      float e[16];
#pragma unroll
      for (int r = 0; r < 16; ++r) e[r] = __builtin_amdgcn_exp2f(z[r]);
      lacc += (((e[0] + e[1]) + (e[2] + e[3])) + ((e[4] + e[5]) + (e[6] + e[7])))
            + (((e[8] + e[9]) + (e[10] + e[11])) + ((e[12] + e[13]) + (e[14] + e[15])));

#if PV_ZERO_SHUFFLE
      // e[4w+j] holds key kt2*32 + w*8 + 4*hi + j for this lane's q = l31:
      // exactly the 32x32x8 A-operand (row = l31, k = 4*hi + j). V B-frag:
      // b64 at V^T[d][kt2*32 + w*8 + 4*hi] (col = d, k = 4*hi + j).
#pragma unroll
      for (int w = 0; w < 4; ++w) {
        union { unsigned u[2]; bf16x4 v; } pu;
        pu.u[0] = pk2(e[4 * w + 0], e[4 * w + 1]);
        pu.u[1] = pk2(e[4 * w + 2], e[4 * w + 3]);
        const int cb = kt2 * 64 + w * 16 + hi * 8;  // byte col in V^T row
        bf16x4 vb0 = *(const bf16x4*)(&Vt[swz64(l31, cb)]);
        bf16x4 vb1 = *(const bf16x4*)(&Vt[swz64(32 + l31, cb)]);
        o0 = __builtin_amdgcn_mfma_f32_32x32x8bf16_1k(pu.v, vb0, o0, 0, 0, 0);
        o1 = __builtin_amdgcn_mfma_f32_32x32x8bf16_1k(pu.v, vb1, o1, 0, 0, 0);
      }
#else
#pragma unroll
      for (int lw = 0; lw < 2; ++lw) {
        const int base = lw * 8;
        unsigned pa0 = pk2(e[base + 0], e[base + 1]);
        unsigned pa1 = pk2(e[base + 2], e[base + 3]);
        unsigned pa2 = pk2(e[base + 4], e[base + 5]);
        unsigned pa3 = pk2(e[base + 6], e[base + 7]);
        // cross-half exchange: hi=0's (pa2,pa3) <-> hi=1's (pa0,pa1).
        unsigned s0 = hi ? pa0 : pa2;
        unsigned s1 = hi ? pa1 : pa3;
        unsigned t0 = __shfl_xor(s0, 32, 64);
        unsigned t1 = __shfl_xor(s1, 32, 64);
        pa2 = hi ? pa2 : t0;
        pa3 = hi ? pa3 : t1;
        pa0 = hi ? t0 : pa0;
        pa1 = hi ? t1 : pa1;
        union { unsigned u[4]; bf16x8 v; } pu;
        pu.u[0] = pa0; pu.u[1] = pa1; pu.u[2] = pa2; pu.u[3] = pa3;
        const int wb = (kt2 * 2 + lw) * 32;  // window byte col in V^T
        bf16x8 vb0 = *(const bf16x8*)(&Vt[swz64(0 + l31, wb + hi * 16)]);
        bf16x8 vb1 = *(const bf16x8*)(&Vt[swz64(32 + l31, wb + hi * 16)]);
        o0 = __builtin_amdgcn_mfma_f32_32x32x16_bf16(pu.v, vb0, o0, 0, 0, 0);
        o1 = __builtin_amdgcn_mfma_f32_32x32x16_bf16(pu.v, vb1, o1, 0, 0, 0);
      }
#endif
    }
  }

  // l: lane and lane+32 hold complementary key-halves of the same q = l31.
  {
    float ltot = lacc + __shfl_xor(lacc, 32, 64);
    if (hi == 0)
      lp[(size_t)bh * SEQ + q0 + wave * 32 + l31] = ltot;
  }

  // O-store: scatter o into LDS [128][64] (q-row major), then coalesced
  // full-line uint4 copy-out. C layout: row q = (r&3)+8*(r>>2)+4*hi, col d.
  __syncthreads();  // all waves done with K/V LDS
  ushort* Ob = &KVbuf[0][0][0];  // 16 KB region
#pragma unroll
  for (int r = 0; r < 16; ++r) {
    int row = wave * 32 + (r & 3) + 8 * (r >> 2) + 4 * hi;
    Ob[row * 64 + l31] = f2b(o0[r]);
    Ob[row * 64 + 32 + l31] = f2b(o1[r]);
  }
  __syncthreads();  // O tile visible
  {
    uint4* dst = (uint4*)(Op + ((size_t)bh * SEQ + q0) * 64);
    const uint4* src = (const uint4*)Ob;
#pragma unroll
    for (int i = 0; i < 4; ++i)
      dst[i * 256 + tid] = src[i * 256 + tid];
  }
}

// ctx = (O1 + O2) / (l1 + l2), routed to (B, T, D_MODEL) bf16
__global__ __launch_bounds__(256) void recombine(const ushort* __restrict__ O1,
                                                 const ushort* __restrict__ O2,
                                                 const float* __restrict__ l1,
                                                 const float* __restrict__ l2,
                                                 ushort* __restrict__ ctx) {
  int idx = blockIdx.x * 256 + threadIdx.x;   // over (BH*T*64)/8 uint4 chunks
  int row = idx >> 3;                         // bh*SEQ + t
  int d8 = idx & 7;
  uint4 a = ((const uint4*)O1)[idx];
  uint4 b = ((const uint4*)O2)[idx];
  float linv = 1.f / (l1[row] + l2[row]);
  uint4 res;
  unsigned* ap = (unsigned*)&a;
  unsigned* bp = (unsigned*)&b;
  unsigned* rp = (unsigned*)&res;
#pragma unroll
  for (int i = 0; i < 4; ++i) {
    float lo = (blo(ap[i]) + blo(bp[i])) * linv;
    float hi = (bhi(ap[i]) + bhi(bp[i])) * linv;
    rp[i] = pk2(lo, hi);
  }
  int bh = row >> 11, t = row & 2047;
  int bb = bh >> 4, h = bh & 15;
  ((uint4*)ctx)[(size_t)(bb * SEQ + t) * 128 + h * 8 + d8] = res;
}

extern "C" void kernel_launch(void* const* d_in, const int* in_sizes, int n_in,
                              void* d_out, int out_size, void* d_ws, size_t ws_size,
                              hipStream_t stream) {
  const float* x  = (const float*)d_in[0];
  const float* Wq = (const float*)d_in[1];
  const float* Wk = (const float*)d_in[2];
  const float* Wv = (const float*)d_in[3];
  const float* Wo = (const float*)d_in[4];
  float* out = (float*)d_out;

  char* ws = (char*)d_ws;
  const size_t MB = 1 << 20;
  ushort* xb   = (ushort*)(ws);             // 8 MB (dead after gemm_qkv -> O2)
  ushort* wqkv = (ushort*)(ws +  8 * MB);   // 6 MB (dead after gemm_qkv -> l1/l2)
  ushort* wob  = (ushort*)(ws + 14 * MB);   // 2 MB (live until gemm_out)
  ushort* Qh   = (ushort*)(ws + 16 * MB);   // 8 MB (BH,T,64)
  ushort* Kh   = (ushort*)(ws + 24 * MB);   // 8 MB (BH,T,64)
  ushort* Vth  = (ushort*)(ws + 32 * MB);   // 8 MB (BH,64,T)
  ushort* ctx  = (ushort*)(ws + 40 * MB);   // 8 MB (B,T,D)

  // split-K partials (regions dead during attn):
  ushort* O1 = (ushort*)d_out;              // 8 MB of the 16 MB output buffer
  ushort* O2 = xb;                          // xb region, dead after gemm_qkv
  float*  l1 = (float*)wqkv;                // 256 KB
  float*  l2 = (float*)(ws + 8 * MB + 256 * 1024);

  cast_all<<<8192, 256, 0, stream>>>(x, Wq, Wk, Wv, Wo, xb, wqkv, wob);

  const float qscale = 0.125f * 1.44269504089f;  // SCALE * log2(e)
  gemm_qkv<<<dim3(3072 / 128, 4096 / 128), 512, 0, stream>>>(xb, wqkv, Qh, Kh, Vth, qscale);

  // 1D grid, 1024 blocks: id = qb*64 + (bh*2+half) -> id%8 fixed per stream
  attn_kernel<<<(SEQ / 128) * BATCH * N_HEADS * 2, 256, 0, stream>>>(
      Qh, Kh, Vth, O1, O2, l1, l2);

  recombine<<<(BATCH * N_HEADS * SEQ * 64 / 8) / 256, 256, 0, stream>>>(O1, O2, l1, l2, ctx);

  gemm_out<<<dim3(1024 / 128, 4096 / 64), 256, 0, stream>>>(ctx, wob, out);
}

// Round 13
// 185.569 us; speedup vs baseline: 1.1976x; 1.0390x over previous
//
#include <hip/hip_runtime.h>
#include <hip/hip_bf16.h>

#define D_MODEL 1024
#define N_HEADS 16
#define HEAD_DIM 64
#define SEQ 2048
#define BATCH 2

typedef __attribute__((ext_vector_type(8))) short bf16x8;
typedef __attribute__((ext_vector_type(4))) short bf16x4;
typedef __attribute__((ext_vector_type(4))) float f32x4;
typedef __attribute__((ext_vector_type(16))) float f32x16;

typedef __attribute__((address_space(3))) unsigned lds_uint;
typedef __attribute__((address_space(1))) const unsigned global_cuint;

__device__ __forceinline__ void async_cp16(const ushort* g, ushort* l) {
  __builtin_amdgcn_global_load_lds((global_cuint*)g, (lds_uint*)l, 16, 0, 0);
}

__device__ __forceinline__ ushort f2b(float f) {
  union { float f; unsigned u; } x; x.f = f;
  unsigned r = x.u + 0x7fffu + ((x.u >> 16) & 1u);
  return (ushort)(r >> 16);
}

// packed f32x2 -> bf16x2; low word = a
__device__ __forceinline__ unsigned pk2(float a, float b) {
  __hip_bfloat162 h = __float22bfloat162_rn(float2{a, b});
  union { __hip_bfloat162 h; unsigned u; } x; x.h = h;
  return x.u;
}

__device__ __forceinline__ float blo(unsigned u) {
  union { unsigned u; float f; } x; x.u = u << 16; return x.f;
}
__device__ __forceinline__ float bhi(unsigned u) {
  union { unsigned u; float f; } x; x.u = u & 0xffff0000u; return x.f;
}

// sigma: swap bits 2 and 3 of a token index (involution, within 16-token
// groups). K stored at row sigma(t) makes the attn S^T C-layout's e[] order
// coincide with the 32x32x16 PV A-operand key order -> zero-shuffle K=16 PV.
__device__ __forceinline__ int sigma23(int t) {
  return (t & ~12) | ((t & 4) << 1) | ((t & 8) >> 1);
}

// XOR-swizzled ushort index into a [64][64] (128 B/row) LDS tile.
// byte_off within row ^= (row&7)<<4. With pre-swizzled global staging
// (source 16B-slot = (l&7)^(l>>3)) the staging write is lane-linear and
// all b128 frag reads distribute exactly 8 lanes per 16B slot.
__device__ __forceinline__ int swz64(int row, int colbyte) {
  return row * 64 + ((colbyte ^ ((row & 7) << 4)) >> 1);
}

// Single fused cast: x (1M uint4) + Wq/Wk/Wv (-> wqkv) + Wo (-> wob).
__global__ __launch_bounds__(256) void cast_all(const float* __restrict__ x,
                                                const float* __restrict__ Wq,
                                                const float* __restrict__ Wk,
                                                const float* __restrict__ Wv,
                                                const float* __restrict__ Wo,
                                                ushort* __restrict__ xb,
                                                ushort* __restrict__ wqkv,
                                                ushort* __restrict__ wob) {
  int idx = blockIdx.x * 256 + threadIdx.x;  // 0 .. 2M-1 (uint4 units)
  const float* in;
  uint2* out;
  if (idx < (1 << 20)) {
    in = x; out = (uint2*)xb;
  } else {
    int j = idx - (1 << 20);
    int w = j >> 18;            // 0..3
    idx = j & 0x3FFFF;          // 256K uint4 per weight
    switch (w) {
      case 0: in = Wq; out = (uint2*)wqkv; break;
      case 1: in = Wk; out = (uint2*)(wqkv) + (1 << 18); break;
      case 2: in = Wv; out = (uint2*)(wqkv) + (2 << 18); break;
      default: in = Wo; out = (uint2*)wob; break;
    }
  }
  float4 v = ((const float4*)in)[idx];
  uint2 o; o.x = pk2(v.x, v.y); o.y = pk2(v.z, v.w);
  out[idx] = o;
}

// Fused QKV projection: A = xb (4096x1024 bf16), Bw = wqkv (3072x1024 bf16).
// 128x128 tile, BK=64. R23 structure: 512-thread blocks (8 waves, 2Mx4N wave
// grid, 64x32 wave tile) -> 16 waves/CU at 64 KB dbuf. R24: K tokens stored
// at sigma23-permuted rows (see sigma23 comment); Q and V^T unchanged.
// n<1024 -> Q (scaled), <2048 -> K, else -> V^T (packed b64 stores along t).
__global__ __launch_bounds__(512, 2) void gemm_qkv(const ushort* __restrict__ A,
                                                   const ushort* __restrict__ Bw,
                                                   ushort* __restrict__ Qh,
                                                   ushort* __restrict__ Kh,
                                                   ushort* __restrict__ Vth,
                                                   float qscale) {
  constexpr int K = 1024;
  const int bm = blockIdx.y * 128;
  const int bn = blockIdx.x * 128;
  const int tid = threadIdx.x;        // 0..511
  const int wave = tid >> 6;          // 0..7
  const int lane = tid & 63;
  const int l16 = lane & 15;
  const int quad = lane >> 4;

  __shared__ ushort As[2][128 * 64];   // 32 KB (dbuf)
  __shared__ ushort Bs[2][128 * 64];   // 32 KB (dbuf)

  const int wm = (wave & 1) * 64;      // 2 M-waves
  const int wn = (wave >> 1) * 32;     // 4 N-waves

  f32x4 acc[4][2];
#pragma unroll
  for (int r = 0; r < 4; ++r)
#pragma unroll
    for (int c = 0; c < 2; ++c) acc[r][c] = (f32x4){0.f, 0.f, 0.f, 0.f};

  // staging: per instruction round, 512 lanes x 16B = 64 rows x 128B.
  const int srow = wave * 8 + (lane >> 3);            // 0..63
  const int csw = (((lane & 7) ^ (lane >> 3)) << 3);  // pre-swizzled col (ushorts)

  // prologue: tile 0 -> buf 0
#pragma unroll
  for (int j = 0; j < 2; ++j) {
    async_cp16(A  + (size_t)(bm + j * 64 + srow) * K + csw, &As[0][(j * 64 + wave * 8) * 64]);
    async_cp16(Bw + (size_t)(bn + j * 64 + srow) * K + csw, &Bs[0][(j * 64 + wave * 8) * 64]);
  }

  constexpr int NIT = K / 64;  // 16
  for (int kt = 0; kt < NIT; ++kt) {
    __syncthreads();  // vmcnt(0) drain: tile kt landed; prior reads of buf^1 done
    const int buf = kt & 1;
    if (kt + 1 < NIT) {
      const int k0 = (kt + 1) * 64;
#pragma unroll
      for (int j = 0; j < 2; ++j) {
        async_cp16(A  + (size_t)(bm + j * 64 + srow) * K + k0 + csw, &As[buf ^ 1][(j * 64 + wave * 8) * 64]);
        async_cp16(Bw + (size_t)(bn + j * 64 + srow) * K + k0 + csw, &Bs[buf ^ 1][(j * 64 + wave * 8) * 64]);
      }
    }

    bf16x8 a[2][4], b[2][2];
#pragma unroll
    for (int ks = 0; ks < 2; ++ks) {
#pragma unroll
      for (int r = 0; r < 4; ++r)
        a[ks][r] = *(const bf16x8*)(&As[buf][swz64(wm + r * 16 + l16, ks * 64 + quad * 16)]);
#pragma unroll
      for (int c = 0; c < 2; ++c)
        b[ks][c] = *(const bf16x8*)(&Bs[buf][swz64(wn + c * 16 + l16, ks * 64 + quad * 16)]);
    }
#pragma unroll
    for (int ks = 0; ks < 2; ++ks)
#pragma unroll
      for (int r = 0; r < 4; ++r)
#pragma unroll
        for (int c = 0; c < 2; ++c)
          acc[r][c] = __builtin_amdgcn_mfma_f32_16x16x32_bf16(a[ks][r], b[ks][c], acc[r][c], 0, 0, 0);
  }

#pragma unroll
  for (int r = 0; r < 4; ++r) {
#pragma unroll
    for (int c = 0; c < 2; ++c) {
      int ncol = bn + wn + c * 16 + l16;   // w uniform per (block,wave,c)
      int w = ncol >> 10;
      int f = ncol & 1023;
      int h = f >> 6, d = f & 63;
      if (w == 2) {
        // V^T: 4 consecutive tokens per lane -> one b64 store (unpermuted)
        int m0 = bm + wm + r * 16 + quad * 4;
        int b = m0 >> 11, t0 = m0 & 2047;
        uint2 pp;
        pp.x = pk2(acc[r][c][0], acc[r][c][1]);
        pp.y = pk2(acc[r][c][2], acc[r][c][3]);
        *(uint2*)(&Vth[((size_t)(b * 1024 + f) << 11) + t0]) = pp;
      } else {
#pragma unroll
        for (int rr = 0; rr < 4; ++rr) {
          float v = acc[r][c][rr];
          int m = bm + wm + r * 16 + quad * 4 + rr;
          int b = m >> 11, t = m & 2047;
          if (w == 0)
            Qh[((size_t)(b * 16 + h) * SEQ + t) * 64 + d] = f2b(v * qscale);
          else
            Kh[((size_t)(b * 16 + h) * SEQ + sigma23(t)) * 64 + d] = f2b(v);
        }
      }
    }
  }
}

// Output projection: A = ctx (4096x1024 bf16), Bw = wob, fp32 out.
// 64x128 tile, BK=64. Dbuf + swizzle (R15).
__global__ __launch_bounds__(256) void gemm_out(const ushort* __restrict__ A,
                                                const ushort* __restrict__ Bw,
                                                float* __restrict__ out) {
  constexpr int K = 1024;
  const int bm = blockIdx.y * 64;
  const int bn = blockIdx.x * 128;
  const int tid = threadIdx.x;
  const int wave = tid >> 6;
  const int lane = tid & 63;
  const int l16 = lane & 15;
  const int quad = lane >> 4;

  __shared__ ushort As[2][64 * 64];    // 16 KB (dbuf)
  __shared__ ushort Bs[2][128 * 64];   // 32 KB (dbuf)

  const int wm = (wave & 1) * 32;
  const int wn = (wave >> 1) * 64;

  f32x4 acc[2][4];
#pragma unroll
  for (int r = 0; r < 2; ++r)
#pragma unroll
    for (int c = 0; c < 4; ++c) acc[r][c] = (f32x4){0.f, 0.f, 0.f, 0.f};

  const int srow = wave * 8 + (lane >> 3);
  const int csw = (((lane & 7) ^ (lane >> 3)) << 3);  // pre-swizzled col (ushorts)

  // prologue: tile 0 -> buf 0
#pragma unroll
  for (int j = 0; j < 2; ++j)
    async_cp16(A + (size_t)(bm + j * 32 + srow) * K + csw, &As[0][(j * 32 + wave * 8) * 64]);
#pragma unroll
  for (int j = 0; j < 4; ++j)
    async_cp16(Bw + (size_t)(bn + j * 32 + srow) * K + csw, &Bs[0][(j * 32 + wave * 8) * 64]);

  constexpr int NIT = K / 64;  // 16
  for (int kt = 0; kt < NIT; ++kt) {
    __syncthreads();
    const int buf = kt & 1;
    if (kt + 1 < NIT) {
      const int k0 = (kt + 1) * 64;
#pragma unroll
      for (int j = 0; j < 2; ++j)
        async_cp16(A + (size_t)(bm + j * 32 + srow) * K + k0 + csw, &As[buf ^ 1][(j * 32 + wave * 8) * 64]);
#pragma unroll
      for (int j = 0; j < 4; ++j)
        async_cp16(Bw + (size_t)(bn + j * 32 + srow) * K + k0 + csw, &Bs[buf ^ 1][(j * 32 + wave * 8) * 64]);
    }

    bf16x8 a[2][2], b[2][4];
#pragma unroll
    for (int ks = 0; ks < 2; ++ks) {
#pragma unroll
      for (int r = 0; r < 2; ++r)
        a[ks][r] = *(const bf16x8*)(&As[buf][swz64(wm + r * 16 + l16, ks * 64 + quad * 16)]);
#pragma unroll
      for (int c = 0; c < 4; ++c)
        b[ks][c] = *(const bf16x8*)(&Bs[buf][swz64(wn + c * 16 + l16, ks * 64 + quad * 16)]);
    }
#pragma unroll
    for (int ks = 0; ks < 2; ++ks)
#pragma unroll
      for (int r = 0; r < 2; ++r)
#pragma unroll
        for (int c = 0; c < 4; ++c)
          acc[r][c] = __builtin_amdgcn_mfma_f32_16x16x32_bf16(a[ks][r], b[ks][c], acc[r][c], 0, 0, 0);
  }

#pragma unroll
  for (int r = 0; r < 2; ++r)
#pragma unroll
    for (int c = 0; c < 4; ++c)
#pragma unroll
      for (int rr = 0; rr < 4; ++rr) {
        int m = bm + wm + r * 16 + quad * 4 + rr;
        int n = bn + wn + c * 16 + l16;
        out[(size_t)m * D_MODEL + n] = acc[r][c][rr];
      }
}

// Flash attention, R24: zero-shuffle PV at K=16 via producer-side key perm.
// K is stored sigma23-permuted (row r holds key sigma(r)); the S^T C-layout
// (row = (j&3)+8*(j>>2)+4*hi for e[8lw+j]) composed with sigma gives key
// 16lw+8hi+j — exactly the 32x32x16 A-operand k-slot order. So the PV A-frag
// is a direct pack pk2(e[b+0],e[b+1])..pk2(e[b+6],e[b+7]): no cross-lane ops
// AND full-K MFMAs (R20's K=8 ran at K=16 cycles -> half throughput; this
// halves PV matrix-pipe time, 192->128 cyc/kt/wave). V^T unpermuted: B-op
// k-slots read linear V columns (R17-verified layout). l and O are key-
// contracted -> permutation-invariant. Everything else = R20/R23.
__global__ __launch_bounds__(256, 2) void attn_kernel(const ushort* __restrict__ Qh,
                                                      const ushort* __restrict__ Kh,
                                                      const ushort* __restrict__ Vth,
                                                      ushort* __restrict__ O1,
                                                      ushort* __restrict__ O2,
                                                      float* __restrict__ l1,
                                                      float* __restrict__ l2) {
  const int id = blockIdx.x;
  const int stream = id & 63;       // bh*2 + half
  const int qb = id >> 6;           // 0..15
  const int bh = stream >> 1;
  const int half = stream & 1;
  const int q0 = qb * 128;
  ushort* __restrict__ Op = half ? O2 : O1;
  float* __restrict__ lp = half ? l2 : l1;

  const int tid = threadIdx.x;
  const int wave = tid >> 6;
  const int lane = tid & 63;
  const int l31 = lane & 31;
  const int hi = lane >> 5;

  __shared__ ushort KVbuf[2][2][64 * 64];  // 32 KB: [buf][0=K,1=V^T], swizzled

  // Q frags (B-op of QK): col = l31 = q, k = d = dc*16 + hi*8 + j
  bf16x8 qf[4];
#pragma unroll
  for (int dc = 0; dc < 4; ++dc)
    qf[dc] = *(const bf16x8*)(Qh + ((size_t)bh * SEQ + q0 + wave * 32 + l31) * 64 + dc * 16 + hi * 8);

  f32x16 o0 = {0.f, 0.f, 0.f, 0.f, 0.f, 0.f, 0.f, 0.f,
               0.f, 0.f, 0.f, 0.f, 0.f, 0.f, 0.f, 0.f};
  f32x16 o1 = o0;
  float lacc = 0.f;

  // async staging geometry: wave fills chunks {2w,2w+1} (8 rows each);
  // source 16B-slot pre-swizzled so the lane-linear LDS write leaves data
  // at the swz64 position.
  const int chunk = wave * 2;
  const int r8 = lane >> 3;
  const int csw = (((lane & 7) ^ r8) << 3);   // ushort offset within 64
  const ushort* kbase = Kh + ((size_t)bh * SEQ + half * 1024) * 64;
  const ushort* vbase = Vth + (size_t)bh * 64 * SEQ + half * 1024;
  const ushort* ksrc = kbase + (size_t)(chunk * 8 + r8) * 64 + csw;   // +kt*4096
  const ushort* vsrc = vbase + (size_t)(chunk * 8 + r8) * SEQ + csw;  // +kt*64

  // prologue: tile 0 -> buf 0
  async_cp16(ksrc,           &KVbuf[0][0][chunk * 512]);
  async_cp16(ksrc + 8 * 64,  &KVbuf[0][0][(chunk + 1) * 512]);
  async_cp16(vsrc,           &KVbuf[0][1][chunk * 512]);
  async_cp16(vsrc + 8 * SEQ, &KVbuf[0][1][(chunk + 1) * 512]);

  constexpr int NIT = 1024 / 64;  // 16
  for (int kt = 0; kt < NIT; ++kt) {
    __syncthreads();  // drains vmcnt: tile kt landed; prior reads of buf^1 done
    const int buf = kt & 1;
    if (kt + 1 < NIT) {
      const ushort* ks = ksrc + (size_t)(kt + 1) * 64 * 64;
      const ushort* vs = vsrc + (kt + 1) * 64;
      async_cp16(ks,           &KVbuf[buf ^ 1][0][chunk * 512]);
      async_cp16(ks + 8 * 64,  &KVbuf[buf ^ 1][0][(chunk + 1) * 512]);
      async_cp16(vs,           &KVbuf[buf ^ 1][1][chunk * 512]);
      async_cp16(vs + 8 * SEQ, &KVbuf[buf ^ 1][1][(chunk + 1) * 512]);
    }
    const ushort* Kt = KVbuf[buf][0];
    const ushort* Vt = KVbuf[buf][1];

#pragma unroll
    for (int kt2 = 0; kt2 < 2; ++kt2) {
      // QK^T: A = K (row = sigma(key) slot = kt2*32 + l31, k = d), 4 d-chunks
      bf16x8 ka0 = *(const bf16x8*)(&Kt[swz64(kt2 * 32 + l31, 0 * 32 + hi * 16)]);
      bf16x8 ka1 = *(const bf16x8*)(&Kt[swz64(kt2 * 32 + l31, 1 * 32 + hi * 16)]);
      bf16x8 ka2 = *(const bf16x8*)(&Kt[swz64(kt2 * 32 + l31, 2 * 32 + hi * 16)]);
      bf16x8 ka3 = *(const bf16x8*)(&Kt[swz64(kt2 * 32 + l31, 3 * 32 + hi * 16)]);
      f32x16 z = {0.f, 0.f, 0.f, 0.f, 0.f, 0.f, 0.f, 0.f,
                  0.f, 0.f, 0.f, 0.f, 0.f, 0.f, 0.f, 0.f};
      z = __builtin_amdgcn_mfma_f32_32x32x16_bf16(ka0, qf[0], z, 0, 0, 0);
      z = __builtin_amdgcn_mfma_f32_32x32x16_bf16(ka1, qf[1], z, 0, 0, 0);
      z = __builtin_amdgcn_mfma_f32_32x32x16_bf16(ka2, qf[2], z, 0, 0, 0);
      z = __builtin_amdgcn_mfma_f32_32x32x16_bf16(ka3, qf[3], z, 0, 0, 0);

      float e[16];
#pragma unroll
      for (int r = 0; r < 16; ++r) e[r] = __builtin_amdgcn_exp2f(z[r]);
      lacc += (((e[0] + e[1]) + (e[2] + e[3])) + ((e[4] + e[5]) + (e[6] + e[7])))
            + (((e[8] + e[9]) + (e[10] + e[11])) + ((e[12] + e[13]) + (e[14] + e[15])));

      // PV, zero-shuffle K=16: e[8lw+j] sits at C-row (j&3)+8(j>>2)+4hi ->
      // key sigma(row) = 16lw + 8hi + j = A k-slot 8hi+j. Direct pack.
#pragma unroll
      for (int lw = 0; lw < 2; ++lw) {
        const int base = lw * 8;
        union { unsigned u[4]; bf16x8 v; } pu;
        pu.u[0] = pk2(e[base + 0], e[base + 1]);
        pu.u[1] = pk2(e[base + 2], e[base + 3]);
        pu.u[2] = pk2(e[base + 4], e[base + 5]);
        pu.u[3] = pk2(e[base + 6], e[base + 7]);
        const int wb = (kt2 * 2 + lw) * 32;  // window byte col in V^T
        bf16x8 vb0 = *(const bf16x8*)(&Vt[swz64(0 + l31, wb + hi * 16)]);
        bf16x8 vb1 = *(const bf16x8*)(&Vt[swz64(32 + l31, wb + hi * 16)]);
        o0 = __builtin_amdgcn_mfma_f32_32x32x16_bf16(pu.v, vb0, o0, 0, 0, 0);
        o1 = __builtin_amdgcn_mfma_f32_32x32x16_bf16(pu.v, vb1, o1, 0, 0, 0);
      }
    }
  }

  // l: lane and lane+32 hold complementary key-halves of the same q = l31.
  {
    float ltot = lacc + __shfl_xor(lacc, 32, 64);
    if (hi == 0)
      lp[(size_t)bh * SEQ + q0 + wave * 32 + l31] = ltot;
  }

  // O-store: scatter o into LDS [128][64] (q-row major), then coalesced
  // full-line uint4 copy-out. C layout: row q = (r&3)+8*(r>>2)+4*hi, col d.
  __syncthreads();  // all waves done with K/V LDS
  ushort* Ob = &KVbuf[0][0][0];  // 16 KB region
#pragma unroll
  for (int r = 0; r < 16; ++r) {
    int row = wave * 32 + (r & 3) + 8 * (r >> 2) + 4 * hi;
    Ob[row * 64 + l31] = f2b(o0[r]);
    Ob[row * 64 + 32 + l31] = f2b(o1[r]);
  }
  __syncthreads();  // O tile visible
  {
    uint4* dst = (uint4*)(Op + ((size_t)bh * SEQ + q0) * 64);
    const uint4* src = (const uint4*)Ob;
#pragma unroll
    for (int i = 0; i < 4; ++i)
      dst[i * 256 + tid] = src[i * 256 + tid];
  }
}

// ctx = (O1 + O2) / (l1 + l2), routed to (B, T, D_MODEL) bf16
__global__ __launch_bounds__(256) void recombine(const ushort* __restrict__ O1,
                                                 const ushort* __restrict__ O2,
                                                 const float* __restrict__ l1,
                                                 const float* __restrict__ l2,
                                                 ushort* __restrict__ ctx) {
  int idx = blockIdx.x * 256 + threadIdx.x;   // over (BH*T*64)/8 uint4 chunks
  int row = idx >> 3;                         // bh*SEQ + t
  int d8 = idx & 7;
  uint4 a = ((const uint4*)O1)[idx];
  uint4 b = ((const uint4*)O2)[idx];
  float linv = 1.f / (l1[row] + l2[row]);
  uint4 res;
  unsigned* ap = (unsigned*)&a;
  unsigned* bp = (unsigned*)&b;
  unsigned* rp = (unsigned*)&res;
#pragma unroll
  for (int i = 0; i < 4; ++i) {
    float lo = (blo(ap[i]) + blo(bp[i])) * linv;
    float hi = (bhi(ap[i]) + bhi(bp[i])) * linv;
    rp[i] = pk2(lo, hi);
  }
  int bh = row >> 11, t = row & 2047;
  int bb = bh >> 4, h = bh & 15;
  ((uint4*)ctx)[(size_t)(bb * SEQ + t) * 128 + h * 8 + d8] = res;
}

extern "C" void kernel_launch(void* const* d_in, const int* in_sizes, int n_in,
                              void* d_out, int out_size, void* d_ws, size_t ws_size,
                              hipStream_t stream) {
  const float* x  = (const float*)d_in[0];
  const float* Wq = (const float*)d_in[1];
  const float* Wk = (const float*)d_in[2];
  const float* Wv = (const float*)d_in[3];
  const float* Wo = (const float*)d_in[4];
  float* out = (float*)d_out;

  char* ws = (char*)d_ws;
  const size_t MB = 1 << 20;
  ushort* xb   = (ushort*)(ws);             // 8 MB (dead after gemm_qkv -> O2)
  ushort* wqkv = (ushort*)(ws +  8 * MB);   // 6 MB (dead after gemm_qkv -> l1/l2)
  ushort* wob  = (ushort*)(ws + 14 * MB);   // 2 MB (live until gemm_out)
  ushort* Qh   = (ushort*)(ws + 16 * MB);   // 8 MB (BH,T,64)
  ushort* Kh   = (ushort*)(ws + 24 * MB);   // 8 MB (BH,T,64)
  ushort* Vth  = (ushort*)(ws + 32 * MB);   // 8 MB (BH,64,T)
  ushort* ctx  = (ushort*)(ws + 40 * MB);   // 8 MB (B,T,D)

  // split-K partials (regions dead during attn):
  ushort* O1 = (ushort*)d_out;              // 8 MB of the 16 MB output buffer
  ushort* O2 = xb;                          // xb region, dead after gemm_qkv
  float*  l1 = (float*)wqkv;                // 256 KB
  float*  l2 = (float*)(ws + 8 * MB + 256 * 1024);

  cast_all<<<8192, 256, 0, stream>>>(x, Wq, Wk, Wv, Wo, xb, wqkv, wob);

  const float qscale = 0.125f * 1.44269504089f;  // SCALE * log2(e)
  gemm_qkv<<<dim3(3072 / 128, 4096 / 128), 512, 0, stream>>>(xb, wqkv, Qh, Kh, Vth, qscale);

  // 1D grid, 1024 blocks: id = qb*64 + (bh*2+half) -> id%8 fixed per stream
  attn_kernel<<<(SEQ / 128) * BATCH * N_HEADS * 2, 256, 0, stream>>>(
      Qh, Kh, Vth, O1, O2, l1, l2);

  recombine<<<(BATCH * N_HEADS * SEQ * 64 / 8) / 256, 256, 0, stream>>>(O1, O2, l1, l2, ctx);

  gemm_out<<<dim3(1024 / 128, 4096 / 64), 256, 0, stream>>>(ctx, wob, out);
}